// Round 6
// baseline (369.255 us; speedup 1.0000x reference)
//
#include <hip/hip_runtime.h>
#include <hip/hip_bf16.h>

#define NN 50000
#define EE 800000
#define DD 128
#define F1 256   // H*HID after conv1
#define F2 128   // OUT

using short8  = __attribute__((ext_vector_type(8))) short;
using floatx4 = __attribute__((ext_vector_type(4))) float;

__device__ inline float bf2f(ushort u) { return __uint_as_float(((unsigned)u) << 16); }
__device__ inline ushort f2bf(float f) {
    unsigned u = __float_as_uint(f);
    u += 0x7fffu + ((u >> 16) & 1u);      // round-to-nearest-even
    return (ushort)(u >> 16);
}

// ---------------- fused prep: hist + emb gather + weight transposes + bc ----------------
#define HB ((EE + 255) / 256)          // 3125
#define GB ((NN + 1) / 2)              // 25000
#define W1B ((DD * F1 + 255) / 256)    // 128
#define W2B ((F1 * F2 + 255) / 256)    // 128
#define WOB ((F2 * F2 + 255) / 256)    // 64

__global__ __launch_bounds__(256) void k_prep(
    const int* __restrict__ edst, int* __restrict__ cnt,
    const int* __restrict__ x, const float* __restrict__ emb, ushort* __restrict__ Ax,
    const float* __restrict__ W1, ushort* __restrict__ W1t,
    const float* __restrict__ W2, ushort* __restrict__ W2t,
    const float* __restrict__ Wo, ushort* __restrict__ Wot,
    const float* __restrict__ b2, const float* __restrict__ bo,
    float* __restrict__ bc) {
    int b = blockIdx.x;
    if (b < HB) {
        int i = b * 256 + threadIdx.x;
        if (i < EE) atomicAdd(&cnt[edst[i]], 1);
    } else if (b < HB + GB) {
        int row = (b - HB) * 2 + (threadIdx.x >> 7);
        if (row < NN) {
            int c = threadIdx.x & 127;
            Ax[(size_t)row * DD + c] = f2bf(emb[(size_t)x[row] * DD + c]);
        }
    } else if (b < HB + GB + W1B) {
        int idx = (b - HB - GB) * 256 + threadIdx.x;
        int k = idx / F1, n = idx % F1;
        W1t[(size_t)n * DD + k] = f2bf(W1[(size_t)k * F1 + n]);
    } else if (b < HB + GB + W1B + W2B) {
        int idx = (b - HB - GB - W1B) * 256 + threadIdx.x;
        int k = idx / F2, n = idx % F2;
        W2t[(size_t)n * F1 + k] = f2bf(W2[(size_t)k * F2 + n]);
    } else if (b < HB + GB + W1B + W2B + WOB) {
        int idx = (b - HB - GB - W1B - W2B) * 256 + threadIdx.x;
        int k = idx / F2, n = idx % F2;
        Wot[(size_t)n * F2 + k] = f2bf(Wo[(size_t)k * F2 + n]);
    } else {
        // bc[j] = b2 @ Wo + bo
        int j = threadIdx.x;
        if (j < F2) {
            float s = bo[j];
            for (int k = 0; k < F2; ++k) s += b2[k] * Wo[(size_t)k * F2 + j];
            bc[j] = s;
        }
    }
}

// ---------------- CSR scan + scatter ----------------
__global__ void k_scan1(const int* __restrict__ cnt, int* __restrict__ out,
                        int* __restrict__ sums) {
    __shared__ int s[256];
    int i = blockIdx.x * 256 + threadIdx.x;
    int v = (i < NN) ? cnt[i] + 1 : 0;   // +1 self-loop
    s[threadIdx.x] = v;
    __syncthreads();
    for (int off = 1; off < 256; off <<= 1) {
        int t = (threadIdx.x >= off) ? s[threadIdx.x - off] : 0;
        __syncthreads();
        s[threadIdx.x] += t;
        __syncthreads();
    }
    if (i < NN) out[i] = s[threadIdx.x] - v;   // exclusive
    if (threadIdx.x == 255) sums[blockIdx.x] = s[255];
}

// each block redundantly scans the block sums, applies its own base
__global__ void k_scan3(int* __restrict__ offsets, const int* __restrict__ sums,
                        int* __restrict__ cursor, int nb) {
    __shared__ int s[256];
    int v = (threadIdx.x < nb) ? sums[threadIdx.x] : 0;
    s[threadIdx.x] = v;
    __syncthreads();
    for (int off = 1; off < 256; off <<= 1) {
        int t = (threadIdx.x >= off) ? s[threadIdx.x - off] : 0;
        __syncthreads();
        s[threadIdx.x] += t;
        __syncthreads();
    }
    int base = (blockIdx.x == 0) ? 0 : s[blockIdx.x - 1];
    int i = blockIdx.x * 256 + threadIdx.x;
    if (i < NN) {
        int o = offsets[i] + base;
        offsets[i] = o;
        cursor[i] = o;
    }
    if (blockIdx.x == 0 && threadIdx.x == 0) offsets[NN] = EE + NN;
}

__global__ void k_scatter(const int* __restrict__ esrc, const int* __restrict__ edst,
                          int* __restrict__ cursor, int* __restrict__ srcs) {
    int i = blockIdx.x * 256 + threadIdx.x;
    if (i < EE) {
        int pos = atomicAdd(&cursor[edst[i]], 1);
        srcs[pos] = esrc[i];
    } else if (i < EE + NN) {
        int n = i - EE;
        int pos = atomicAdd(&cursor[n], 1);
        srcs[pos] = n;
    }
}

// ---------------- bf16 MFMA GEMM with fused attention-logit epilogue ----------------
// MODE 0: bf16 out.  MODE 1: bf16 out + 8-head AL.  MODE 2: bf16 out + 1-head AL.
template<int K, int MODE>
__global__ __launch_bounds__(256, 2) void k_mfma_gemm(
    const ushort* __restrict__ A, const ushort* __restrict__ Bt,
    void* __restrict__ Cout, int ldc, const float* __restrict__ bias,
    const float* __restrict__ avs, const float* __restrict__ avd,
    float* __restrict__ out_s, float* __restrict__ out_d) {
    __shared__ ushort As[128][72];   // [m][k]
    __shared__ ushort Bs[128][72];   // [n][k]
    __shared__ float als[2][128], ald[2][128];   // MODE 2 cross-wave combine
    const int t    = threadIdx.x;
    const int lane = t & 63;
    const int w    = t >> 6;
    const int wr   = w >> 1, wc = w & 1;
    const int m0   = blockIdx.x * 128;
    const int n0   = blockIdx.y * 128;
    floatx4 acc[4][4] = {};
    for (int k0 = 0; k0 < K; k0 += 64) {
        #pragma unroll
        for (int p = 0; p < 4; ++p) {            // 4*2048 = full 128x64 tile
            int linear = p * 2048 + t * 8;
            int row = linear >> 6;
            int col = linear & 63;
            short8 va = {};
            int gm = m0 + row;
            if (gm < NN) va = *(const short8*)(A + (size_t)gm * K + k0 + col);
            *(short8*)&As[row][col] = va;
            short8 vb = *(const short8*)(Bt + (size_t)(n0 + row) * K + k0 + col);
            *(short8*)&Bs[row][col] = vb;
        }
        __syncthreads();
        #pragma unroll
        for (int kk = 0; kk < 64; kk += 32) {
            const int q8 = (lane >> 4) * 8;
            short8 af[4], bf[4];
            #pragma unroll
            for (int i = 0; i < 4; ++i)
                af[i] = *(const short8*)&As[wr * 64 + i * 16 + (lane & 15)][kk + q8];
            #pragma unroll
            for (int j = 0; j < 4; ++j)
                bf[j] = *(const short8*)&Bs[wc * 64 + j * 16 + (lane & 15)][kk + q8];
            #pragma unroll
            for (int i = 0; i < 4; ++i)
                #pragma unroll
                for (int j = 0; j < 4; ++j)
                    acc[i][j] = __builtin_amdgcn_mfma_f32_16x16x32_bf16(
                        af[i], bf[j], acc[i][j], 0, 0, 0);
        }
        __syncthreads();
    }
    const int q  = lane >> 4;
    const int r0 = q * 4;
    const int cc = lane & 15;
    float as0 = 0, as1 = 0, as2 = 0, as3 = 0, ad0 = 0, ad1 = 0, ad2 = 0, ad3 = 0;
    if (MODE == 1 || MODE == 2) {
        as0 = avs[n0 + wc * 64 +  0 + cc]; ad0 = avd[n0 + wc * 64 +  0 + cc];
        as1 = avs[n0 + wc * 64 + 16 + cc]; ad1 = avd[n0 + wc * 64 + 16 + cc];
        as2 = avs[n0 + wc * 64 + 32 + cc]; ad2 = avd[n0 + wc * 64 + 32 + cc];
        as3 = avs[n0 + wc * 64 + 48 + cc]; ad3 = avd[n0 + wc * 64 + 48 + cc];
    }
    #pragma unroll
    for (int i = 0; i < 4; ++i) {
        #pragma unroll
        for (int r = 0; r < 4; ++r) {
            int m = m0 + wr * 64 + i * 16 + r0 + r;
            if (MODE == 1) {
                float hs0 = acc[i][0][r] * as0 + acc[i][1][r] * as1;
                float hs1 = acc[i][2][r] * as2 + acc[i][3][r] * as3;
                float hd0 = acc[i][0][r] * ad0 + acc[i][1][r] * ad1;
                float hd1 = acc[i][2][r] * ad2 + acc[i][3][r] * ad3;
                #pragma unroll
                for (int mask = 1; mask < 16; mask <<= 1) {
                    hs0 += __shfl_xor(hs0, mask);
                    hs1 += __shfl_xor(hs1, mask);
                    hd0 += __shfl_xor(hd0, mask);
                    hd1 += __shfl_xor(hd1, mask);
                }
                if (cc == 0 && m < NN) {
                    int gh = (n0 >> 5) + wc * 2;
                    out_s[m * 8 + gh] = hs0;   out_s[m * 8 + gh + 1] = hs1;
                    out_d[m * 8 + gh] = hd0;   out_d[m * 8 + gh + 1] = hd1;
                }
            }
            if (MODE == 2) {
                float ps = acc[i][0][r] * as0 + acc[i][1][r] * as1
                         + acc[i][2][r] * as2 + acc[i][3][r] * as3;
                float pd = acc[i][0][r] * ad0 + acc[i][1][r] * ad1
                         + acc[i][2][r] * ad2 + acc[i][3][r] * ad3;
                #pragma unroll
                for (int mask = 1; mask < 16; mask <<= 1) {
                    ps += __shfl_xor(ps, mask);
                    pd += __shfl_xor(pd, mask);
                }
                if (cc == 0) {
                    int lr = wr * 64 + i * 16 + r0 + r;
                    als[wc][lr] = ps;
                    ald[wc][lr] = pd;
                }
            }
            if (m < NN) {
                #pragma unroll
                for (int j = 0; j < 4; ++j) {
                    int n = n0 + wc * 64 + j * 16 + cc;
                    ((ushort*)Cout)[(size_t)m * ldc + n] = f2bf(acc[i][j][r]);
                }
            }
        }
    }
    if (MODE == 2) {
        __syncthreads();
        if (t < 128) {
            int m = m0 + t;
            if (m < NN) {
                out_s[m] = als[0][t] + als[1][t];
                out_d[m] = ald[0][t] + ald[1][t];
            }
        }
    }
}

__device__ inline float lrelu(float x) { return x > 0.f ? x : 0.2f * x; }

// ---------------- GAT aggregation, one wave per destination node ----------------
__global__ __launch_bounds__(256) void k_agg1(
    const int* __restrict__ offsets, const int* __restrict__ srcs,
    const ushort* __restrict__ h1, const float* __restrict__ a1s,
    const float* __restrict__ a1d, const float* __restrict__ b1,
    ushort* __restrict__ out1) {
    __shared__ float atab[4][512];   // [wave][edge*8+head]
    __shared__ int   stab[4][64];    // [wave][edge]
    const int w = threadIdx.x >> 6;
    const int d = blockIdx.x * 4 + w;
    if (d >= NN) return;
    const int lane = threadIdx.x & 63;
    const int beg = offsets[d], end = offsets[d + 1];
    const int e8 = lane >> 3, h8 = lane & 7;
    const float ad = a1d[d * 8 + h8];
    float m = -1e30f, den = 0.f;
    for (int i = beg + e8; i < end; i += 8) {
        int s = srcs[i];
        float v = lrelu(a1s[s * 8 + h8] + ad);
        float nm = fmaxf(m, v);
        den = den * __expf(m - nm) + __expf(v - nm);
        m = nm;
    }
    #pragma unroll
    for (int mask = 8; mask < 64; mask <<= 1) {
        float om = __shfl_xor(m, mask);
        float od = __shfl_xor(den, mask);
        float nm = fmaxf(m, om);
        den = den * __expf(m - nm) + od * __expf(om - nm);
        m = nm;
    }
    float rden = 1.f / (den + 1e-16f);
    float4 acc = make_float4(0.f, 0.f, 0.f, 0.f);
    const int hh = lane >> 3;
    for (int tb = beg; tb < end; tb += 64) {
        int cnt = min(64, end - tb);
        if (lane < cnt) stab[w][lane] = srcs[tb + lane];
        int np = cnt * 8;
        for (int p = lane; p < np; p += 64) {       // p&7 == h8 always
            int s = stab[w][p >> 3];
            float v = lrelu(a1s[s * 8 + h8] + ad);
            atab[w][p] = __expf(v - m) * rden;
        }
        int e = 0;
        for (; e + 8 <= cnt; e += 8) {
            ushort4 u[8]; float a[8];
            #pragma unroll
            for (int jj = 0; jj < 8; ++jj) {
                int s = stab[w][e + jj];
                u[jj] = *(const ushort4*)(h1 + (size_t)s * F1 + lane * 4);
                a[jj] = atab[w][(e + jj) * 8 + hh];
            }
            #pragma unroll
            for (int jj = 0; jj < 8; ++jj) {
                acc.x += a[jj] * bf2f(u[jj].x);
                acc.y += a[jj] * bf2f(u[jj].y);
                acc.z += a[jj] * bf2f(u[jj].z);
                acc.w += a[jj] * bf2f(u[jj].w);
            }
        }
        for (; e < cnt; ++e) {
            int s = stab[w][e];
            float alpha = atab[w][e * 8 + hh];
            ushort4 u = *(const ushort4*)(h1 + (size_t)s * F1 + lane * 4);
            acc.x += alpha * bf2f(u.x); acc.y += alpha * bf2f(u.y);
            acc.z += alpha * bf2f(u.z); acc.w += alpha * bf2f(u.w);
        }
    }
    float4 bb = *(const float4*)(b1 + lane * 4);
    ushort4 o;
    o.x = f2bf(acc.x + bb.x); o.y = f2bf(acc.y + bb.y);
    o.z = f2bf(acc.z + bb.z); o.w = f2bf(acc.w + bb.w);
    *(ushort4*)(out1 + (size_t)d * F1 + lane * 4) = o;
}

// agg2 over h3 = h2 @ Wo; writes FINAL fp32 out with bc = b2@Wo + bo.
__global__ __launch_bounds__(256) void k_agg2(
    const int* __restrict__ offsets, const int* __restrict__ srcs,
    const ushort* __restrict__ h3, const float* __restrict__ a2s,
    const float* __restrict__ a2d, const float* __restrict__ bc,
    float* __restrict__ out) {
    __shared__ float atab[4][64];
    __shared__ int   stab[4][64];
    const int w = threadIdx.x >> 6;
    const int d = blockIdx.x * 4 + w;
    if (d >= NN) return;
    const int lane = threadIdx.x & 63;
    const int beg = offsets[d], end = offsets[d + 1];
    const float ad = a2d[d];
    float m = -1e30f, den = 0.f;
    for (int i = beg + lane; i < end; i += 64) {
        int s = srcs[i];
        float v = lrelu(a2s[s] + ad);
        float nm = fmaxf(m, v);
        den = den * __expf(m - nm) + __expf(v - nm);
        m = nm;
    }
    #pragma unroll
    for (int mask = 1; mask < 64; mask <<= 1) {
        float om = __shfl_xor(m, mask);
        float od = __shfl_xor(den, mask);
        float nm = fmaxf(m, om);
        den = den * __expf(m - nm) + od * __expf(om - nm);
        m = nm;
    }
    float rden = 1.f / (den + 1e-16f);
    float2 acc = make_float2(0.f, 0.f);
    for (int tb = beg; tb < end; tb += 64) {
        int cnt = min(64, end - tb);
        if (lane < cnt) {
            int s = srcs[tb + lane];
            stab[w][lane] = s;
            atab[w][lane] = __expf(lrelu(a2s[s] + ad) - m) * rden;
        }
        int e = 0;
        for (; e + 8 <= cnt; e += 8) {
            ushort2 u[8]; float a[8];
            #pragma unroll
            for (int jj = 0; jj < 8; ++jj) {
                int s = stab[w][e + jj];
                u[jj] = *(const ushort2*)(h3 + (size_t)s * F2 + lane * 2);
                a[jj] = atab[w][e + jj];
            }
            #pragma unroll
            for (int jj = 0; jj < 8; ++jj) {
                acc.x += a[jj] * bf2f(u[jj].x);
                acc.y += a[jj] * bf2f(u[jj].y);
            }
        }
        for (; e < cnt; ++e) {
            int s = stab[w][e];
            float alpha = atab[w][e];
            ushort2 u = *(const ushort2*)(h3 + (size_t)s * F2 + lane * 2);
            acc.x += alpha * bf2f(u.x); acc.y += alpha * bf2f(u.y);
        }
    }
    float2 bb = *(const float2*)(bc + lane * 2);
    *(float2*)(out + (size_t)d * F2 + lane * 2) = make_float2(acc.x + bb.x, acc.y + bb.y);
}

extern "C" void kernel_launch(void* const* d_in, const int* in_sizes, int n_in,
                              void* d_out, int out_size, void* d_ws, size_t ws_size,
                              hipStream_t stream) {
    const int*   x      = (const int*)d_in[0];
    const int*   edge   = (const int*)d_in[1];   // [2][E]
    const float* emb    = (const float*)d_in[2];
    const float* W1     = (const float*)d_in[3];
    const float* a_src1 = (const float*)d_in[4];
    const float* a_dst1 = (const float*)d_in[5];
    const float* b1     = (const float*)d_in[6];
    const float* W2     = (const float*)d_in[7];
    const float* a_src2 = (const float*)d_in[8];
    const float* a_dst2 = (const float*)d_in[9];
    const float* b2     = (const float*)d_in[10];
    const float* Wo     = (const float*)d_in[11];
    const float* bo     = (const float*)d_in[12];
    float* out = (float*)d_out;

    char* w = (char*)d_ws;
    auto alloc = [&](size_t bytes) {
        char* p = w;
        w += (bytes + 255) & ~(size_t)255;
        return p;
    };
    int*    offsets = (int*)alloc((NN + 1) * sizeof(int));
    int*    cursor  = (int*)alloc(NN * sizeof(int));
    int*    sums    = (int*)alloc(256 * sizeof(int));
    int*    srcs    = (int*)alloc((size_t)(EE + NN) * sizeof(int));
    ushort* Ax      = (ushort*)alloc((size_t)NN * DD * sizeof(ushort));
    ushort* W1t     = (ushort*)alloc((size_t)DD * F1 * sizeof(ushort));
    ushort* W2t     = (ushort*)alloc((size_t)F1 * F2 * sizeof(ushort));
    ushort* Wot     = (ushort*)alloc((size_t)F2 * F2 * sizeof(ushort));
    ushort* h1      = (ushort*)alloc((size_t)NN * F1 * sizeof(ushort));
    ushort* out1    = (ushort*)alloc((size_t)NN * F1 * sizeof(ushort));
    ushort* h2      = (ushort*)alloc((size_t)NN * F2 * sizeof(ushort));
    ushort* h3      = (ushort*)alloc((size_t)NN * F2 * sizeof(ushort));
    float*  a1s     = (float*)alloc((size_t)NN * 8 * sizeof(float));
    float*  a1d     = (float*)alloc((size_t)NN * 8 * sizeof(float));
    float*  bc      = (float*)alloc(F2 * sizeof(float));
    float*  a2s     = a1s;
    float*  a2d     = a1d;

    const int* esrc = edge;
    const int* edst = edge + EE;

    const int NB = (NN + 255) / 256;        // 196

    // CSR build + converts
    hipMemsetAsync(cursor, 0, NN * sizeof(int), stream);
    k_prep<<<HB + GB + W1B + W2B + WOB + 1, 256, 0, stream>>>(
        edst, cursor, x, emb, Ax, W1, W1t, W2, W2t, Wo, Wot, b2, bo, bc);
    k_scan1<<<NB, 256, 0, stream>>>(cursor, offsets, sums);
    k_scan3<<<NB, 256, 0, stream>>>(offsets, sums, cursor, NB);
    k_scatter<<<(EE + NN + 255) / 256, 256, 0, stream>>>(esrc, edst, cursor, srcs);

    const int MT = (NN + 127) / 128;        // 391

    // conv1 (GEMM + fused al1)
    k_mfma_gemm<DD, 1><<<dim3(MT, F1 / 128), 256, 0, stream>>>(
        Ax, W1t, h1, F1, nullptr, a_src1, a_dst1, a1s, a1d);
    k_agg1<<<(NN + 3) / 4, 256, 0, stream>>>(offsets, srcs, h1, a1s, a1d, b1, out1);

    // conv2 (GEMM + fused al2)
    k_mfma_gemm<F1, 2><<<dim3(MT, 1), 256, 0, stream>>>(
        out1, W2t, h2, F2, nullptr, a_src2, a_dst2, a2s, a2d);

    // h3 = h2 @ Wo (bf16)
    k_mfma_gemm<F2, 0><<<dim3(MT, 1), 256, 0, stream>>>(
        h2, Wot, h3, F2, nullptr, nullptr, nullptr, nullptr, nullptr);

    // final aggregation writes fp32 out directly
    k_agg2<<<(NN + 3) / 4, 256, 0, stream>>>(offsets, srcs, h3, a2s, a2d, bc, out);
}

// Round 7
// 364.212 us; speedup vs baseline: 1.0138x; 1.0138x over previous
//
#include <hip/hip_runtime.h>
#include <hip/hip_bf16.h>

#define NN 50000
#define EE 800000
#define DD 128
#define F1 256   // H*HID after conv1
#define F2 128   // OUT

using short8  = __attribute__((ext_vector_type(8))) short;
using floatx4 = __attribute__((ext_vector_type(4))) float;

__device__ inline float bf2f(ushort u) { return __uint_as_float(((unsigned)u) << 16); }
__device__ inline ushort f2bf(float f) {
    unsigned u = __float_as_uint(f);
    u += 0x7fffu + ((u >> 16) & 1u);      // round-to-nearest-even
    return (ushort)(u >> 16);
}

// ---------------- fused prep: hist + emb gather + weight transposes + bc ----------------
#define HB ((EE + 255) / 256)          // 3125
#define GB ((NN + 1) / 2)              // 25000
#define W1B ((DD * F1 + 255) / 256)    // 128
#define W2B ((F1 * F2 + 255) / 256)    // 128
#define WOB ((F2 * F2 + 255) / 256)    // 64

__global__ __launch_bounds__(256) void k_prep(
    const int* __restrict__ edst, int* __restrict__ cnt,
    const int* __restrict__ x, const float* __restrict__ emb, ushort* __restrict__ Ax,
    const float* __restrict__ W1, ushort* __restrict__ W1t,
    const float* __restrict__ W2, ushort* __restrict__ W2t,
    const float* __restrict__ Wo, ushort* __restrict__ Wot,
    const float* __restrict__ b2, const float* __restrict__ bo,
    float* __restrict__ bc) {
    int b = blockIdx.x;
    if (b < HB) {
        int i = b * 256 + threadIdx.x;
        if (i < EE) atomicAdd(&cnt[edst[i]], 1);
    } else if (b < HB + GB) {
        int row = (b - HB) * 2 + (threadIdx.x >> 7);
        if (row < NN) {
            int c = threadIdx.x & 127;
            Ax[(size_t)row * DD + c] = f2bf(emb[(size_t)x[row] * DD + c]);
        }
    } else if (b < HB + GB + W1B) {
        int idx = (b - HB - GB) * 256 + threadIdx.x;
        int k = idx / F1, n = idx % F1;
        W1t[(size_t)n * DD + k] = f2bf(W1[(size_t)k * F1 + n]);
    } else if (b < HB + GB + W1B + W2B) {
        int idx = (b - HB - GB - W1B) * 256 + threadIdx.x;
        int k = idx / F2, n = idx % F2;
        W2t[(size_t)n * F1 + k] = f2bf(W2[(size_t)k * F2 + n]);
    } else if (b < HB + GB + W1B + W2B + WOB) {
        int idx = (b - HB - GB - W1B - W2B) * 256 + threadIdx.x;
        int k = idx / F2, n = idx % F2;
        Wot[(size_t)n * F2 + k] = f2bf(Wo[(size_t)k * F2 + n]);
    } else {
        int j = threadIdx.x;
        if (j < F2) {
            float s = bo[j];
            for (int k = 0; k < F2; ++k) s += b2[k] * Wo[(size_t)k * F2 + j];
            bc[j] = s;
        }
    }
}

// ---------------- CSR scan + scatter ----------------
__global__ void k_scan1(const int* __restrict__ cnt, int* __restrict__ out,
                        int* __restrict__ sums) {
    __shared__ int s[256];
    int i = blockIdx.x * 256 + threadIdx.x;
    int v = (i < NN) ? cnt[i] + 1 : 0;   // +1 self-loop
    s[threadIdx.x] = v;
    __syncthreads();
    for (int off = 1; off < 256; off <<= 1) {
        int t = (threadIdx.x >= off) ? s[threadIdx.x - off] : 0;
        __syncthreads();
        s[threadIdx.x] += t;
        __syncthreads();
    }
    if (i < NN) out[i] = s[threadIdx.x] - v;   // exclusive
    if (threadIdx.x == 255) sums[blockIdx.x] = s[255];
}

__global__ void k_scan3(int* __restrict__ offsets, const int* __restrict__ sums,
                        int* __restrict__ cursor, int nb) {
    __shared__ int s[256];
    int v = (threadIdx.x < nb) ? sums[threadIdx.x] : 0;
    s[threadIdx.x] = v;
    __syncthreads();
    for (int off = 1; off < 256; off <<= 1) {
        int t = (threadIdx.x >= off) ? s[threadIdx.x - off] : 0;
        __syncthreads();
        s[threadIdx.x] += t;
        __syncthreads();
    }
    int base = (blockIdx.x == 0) ? 0 : s[blockIdx.x - 1];
    int i = blockIdx.x * 256 + threadIdx.x;
    if (i < NN) {
        int o = offsets[i] + base;
        offsets[i] = o;
        cursor[i] = o;
    }
    if (blockIdx.x == 0 && threadIdx.x == 0) offsets[NN] = EE + NN;
}

__global__ void k_scatter(const int* __restrict__ esrc, const int* __restrict__ edst,
                          int* __restrict__ cursor, int* __restrict__ srcs) {
    int i = blockIdx.x * 256 + threadIdx.x;
    if (i < EE) {
        int pos = atomicAdd(&cursor[edst[i]], 1);
        srcs[pos] = esrc[i];
    } else if (i < EE + NN) {
        int n = i - EE;
        int pos = atomicAdd(&cursor[n], 1);
        srcs[pos] = n;
    }
}

// ---------------- bf16 MFMA GEMM with fused attention-logit epilogue ----------------
// MODE 0: bf16 out.  MODE 1: bf16 out + 8-head AL.  MODE 2: bf16 out + 1-head AL.
template<int K, int MODE>
__global__ __launch_bounds__(256, 2) void k_mfma_gemm(
    const ushort* __restrict__ A, const ushort* __restrict__ Bt,
    void* __restrict__ Cout, int ldc, const float* __restrict__ bias,
    const float* __restrict__ avs, const float* __restrict__ avd,
    float* __restrict__ out_s, float* __restrict__ out_d) {
    __shared__ ushort As[128][72];   // [m][k]
    __shared__ ushort Bs[128][72];   // [n][k]
    __shared__ float als[2][128], ald[2][128];   // MODE 2 cross-wave combine
    const int t    = threadIdx.x;
    const int lane = t & 63;
    const int w    = t >> 6;
    const int wr   = w >> 1, wc = w & 1;
    const int m0   = blockIdx.x * 128;
    const int n0   = blockIdx.y * 128;
    floatx4 acc[4][4] = {};
    for (int k0 = 0; k0 < K; k0 += 64) {
        #pragma unroll
        for (int p = 0; p < 4; ++p) {
            int linear = p * 2048 + t * 8;
            int row = linear >> 6;
            int col = linear & 63;
            short8 va = {};
            int gm = m0 + row;
            if (gm < NN) va = *(const short8*)(A + (size_t)gm * K + k0 + col);
            *(short8*)&As[row][col] = va;
            short8 vb = *(const short8*)(Bt + (size_t)(n0 + row) * K + k0 + col);
            *(short8*)&Bs[row][col] = vb;
        }
        __syncthreads();
        #pragma unroll
        for (int kk = 0; kk < 64; kk += 32) {
            const int q8 = (lane >> 4) * 8;
            short8 af[4], bf[4];
            #pragma unroll
            for (int i = 0; i < 4; ++i)
                af[i] = *(const short8*)&As[wr * 64 + i * 16 + (lane & 15)][kk + q8];
            #pragma unroll
            for (int j = 0; j < 4; ++j)
                bf[j] = *(const short8*)&Bs[wc * 64 + j * 16 + (lane & 15)][kk + q8];
            #pragma unroll
            for (int i = 0; i < 4; ++i)
                #pragma unroll
                for (int j = 0; j < 4; ++j)
                    acc[i][j] = __builtin_amdgcn_mfma_f32_16x16x32_bf16(
                        af[i], bf[j], acc[i][j], 0, 0, 0);
        }
        __syncthreads();
    }
    const int q  = lane >> 4;
    const int r0 = q * 4;
    const int cc = lane & 15;
    float as0 = 0, as1 = 0, as2 = 0, as3 = 0, ad0 = 0, ad1 = 0, ad2 = 0, ad3 = 0;
    if (MODE == 1 || MODE == 2) {
        as0 = avs[n0 + wc * 64 +  0 + cc]; ad0 = avd[n0 + wc * 64 +  0 + cc];
        as1 = avs[n0 + wc * 64 + 16 + cc]; ad1 = avd[n0 + wc * 64 + 16 + cc];
        as2 = avs[n0 + wc * 64 + 32 + cc]; ad2 = avd[n0 + wc * 64 + 32 + cc];
        as3 = avs[n0 + wc * 64 + 48 + cc]; ad3 = avd[n0 + wc * 64 + 48 + cc];
    }
    #pragma unroll
    for (int i = 0; i < 4; ++i) {
        #pragma unroll
        for (int r = 0; r < 4; ++r) {
            int m = m0 + wr * 64 + i * 16 + r0 + r;
            if (MODE == 1) {
                float hs0 = acc[i][0][r] * as0 + acc[i][1][r] * as1;
                float hs1 = acc[i][2][r] * as2 + acc[i][3][r] * as3;
                float hd0 = acc[i][0][r] * ad0 + acc[i][1][r] * ad1;
                float hd1 = acc[i][2][r] * ad2 + acc[i][3][r] * ad3;
                #pragma unroll
                for (int mask = 1; mask < 16; mask <<= 1) {
                    hs0 += __shfl_xor(hs0, mask);
                    hs1 += __shfl_xor(hs1, mask);
                    hd0 += __shfl_xor(hd0, mask);
                    hd1 += __shfl_xor(hd1, mask);
                }
                if (cc == 0 && m < NN) {
                    int gh = (n0 >> 5) + wc * 2;
                    out_s[m * 8 + gh] = hs0;   out_s[m * 8 + gh + 1] = hs1;
                    out_d[m * 8 + gh] = hd0;   out_d[m * 8 + gh + 1] = hd1;
                }
            }
            if (MODE == 2) {
                float ps = acc[i][0][r] * as0 + acc[i][1][r] * as1
                         + acc[i][2][r] * as2 + acc[i][3][r] * as3;
                float pd = acc[i][0][r] * ad0 + acc[i][1][r] * ad1
                         + acc[i][2][r] * ad2 + acc[i][3][r] * ad3;
                #pragma unroll
                for (int mask = 1; mask < 16; mask <<= 1) {
                    ps += __shfl_xor(ps, mask);
                    pd += __shfl_xor(pd, mask);
                }
                if (cc == 0) {
                    int lr = wr * 64 + i * 16 + r0 + r;
                    als[wc][lr] = ps;
                    ald[wc][lr] = pd;
                }
            }
            if (m < NN) {
                #pragma unroll
                for (int j = 0; j < 4; ++j) {
                    int n = n0 + wc * 64 + j * 16 + cc;
                    ((ushort*)Cout)[(size_t)m * ldc + n] = f2bf(acc[i][j][r]);
                }
            }
        }
    }
    if (MODE == 2) {
        __syncthreads();
        if (t < 128) {
            int m = m0 + t;
            if (m < NN) {
                out_s[m] = als[0][t] + als[1][t];
                out_d[m] = ald[0][t] + ald[1][t];
            }
        }
    }
}

__device__ inline float lrelu(float x) { return x > 0.f ? x : 0.2f * x; }

// ---------------- GAT aggregation ----------------
// Fast path (deg <= 128): pass1 loads srcs+a1s ONCE, caches raw logits in LDS;
// pass2 normalizes in LDS only; pass3 gathers h rows. Slow path = old 3-pass tiles.
__global__ __launch_bounds__(256) void k_agg1(
    const int* __restrict__ offsets, const int* __restrict__ srcs,
    const ushort* __restrict__ h1, const float* __restrict__ a1s,
    const float* __restrict__ a1d, const float* __restrict__ b1,
    ushort* __restrict__ out1) {
    __shared__ float atab[4][1024];   // [wave][edge*8+head], deg<=128
    __shared__ int   stab[4][128];
    const int w = threadIdx.x >> 6;
    const int d = blockIdx.x * 4 + w;
    if (d >= NN) return;
    const int lane = threadIdx.x & 63;
    const int beg = offsets[d], end = offsets[d + 1];
    const int deg = end - beg;
    const int e8 = lane >> 3, h8 = lane & 7;
    const float ad = a1d[d * 8 + h8];
    const int hh = lane >> 3;
    float4 acc = make_float4(0.f, 0.f, 0.f, 0.f);

    if (deg <= 128) {
        float m = -1e30f, den = 0.f;
        for (int e = e8; e < deg; e += 8) {
            int s = srcs[beg + e];
            if (h8 == 0) stab[w][e] = s;
            float v = lrelu(a1s[s * 8 + h8] + ad);
            atab[w][e * 8 + h8] = v;            // raw logit
            float nm = fmaxf(m, v);
            den = den * __expf(m - nm) + __expf(v - nm);
            m = nm;
        }
        #pragma unroll
        for (int mask = 8; mask < 64; mask <<= 1) {
            float om = __shfl_xor(m, mask);
            float od = __shfl_xor(den, mask);
            float nm = fmaxf(m, om);
            den = den * __expf(m - nm) + od * __expf(om - nm);
            m = nm;
        }
        float rden = 1.f / (den + 1e-16f);
        // LDS-only normalize: p & 7 == h8 for stride 64
        for (int p = lane; p < deg * 8; p += 64)
            atab[w][p] = __expf(atab[w][p] - m) * rden;
        int e = 0;
        for (; e + 8 <= deg; e += 8) {
            ushort4 u[8]; float a[8];
            #pragma unroll
            for (int jj = 0; jj < 8; ++jj) {
                int s = stab[w][e + jj];
                u[jj] = *(const ushort4*)(h1 + (size_t)s * F1 + lane * 4);
                a[jj] = atab[w][(e + jj) * 8 + hh];
            }
            #pragma unroll
            for (int jj = 0; jj < 8; ++jj) {
                acc.x += a[jj] * bf2f(u[jj].x);
                acc.y += a[jj] * bf2f(u[jj].y);
                acc.z += a[jj] * bf2f(u[jj].z);
                acc.w += a[jj] * bf2f(u[jj].w);
            }
        }
        for (; e < deg; ++e) {
            int s = stab[w][e];
            float alpha = atab[w][e * 8 + hh];
            ushort4 u = *(const ushort4*)(h1 + (size_t)s * F1 + lane * 4);
            acc.x += alpha * bf2f(u.x); acc.y += alpha * bf2f(u.y);
            acc.z += alpha * bf2f(u.z); acc.w += alpha * bf2f(u.w);
        }
    } else {
        // slow path (rare): 3-pass with 64-edge tiles
        float m = -1e30f, den = 0.f;
        for (int i = beg + e8; i < end; i += 8) {
            int s = srcs[i];
            float v = lrelu(a1s[s * 8 + h8] + ad);
            float nm = fmaxf(m, v);
            den = den * __expf(m - nm) + __expf(v - nm);
            m = nm;
        }
        #pragma unroll
        for (int mask = 8; mask < 64; mask <<= 1) {
            float om = __shfl_xor(m, mask);
            float od = __shfl_xor(den, mask);
            float nm = fmaxf(m, om);
            den = den * __expf(m - nm) + od * __expf(om - nm);
            m = nm;
        }
        float rden = 1.f / (den + 1e-16f);
        for (int tb = beg; tb < end; tb += 64) {
            int cnt = min(64, end - tb);
            if (lane < cnt) stab[w][lane] = srcs[tb + lane];
            int np = cnt * 8;
            for (int p = lane; p < np; p += 64) {
                int s = stab[w][p >> 3];
                float v = lrelu(a1s[s * 8 + h8] + ad);
                atab[w][p] = __expf(v - m) * rden;
            }
            for (int e = 0; e < cnt; ++e) {
                int s = stab[w][e];
                float alpha = atab[w][e * 8 + hh];
                ushort4 u = *(const ushort4*)(h1 + (size_t)s * F1 + lane * 4);
                acc.x += alpha * bf2f(u.x); acc.y += alpha * bf2f(u.y);
                acc.z += alpha * bf2f(u.z); acc.w += alpha * bf2f(u.w);
            }
        }
    }
    float4 bb = *(const float4*)(b1 + lane * 4);
    ushort4 o;
    o.x = f2bf(acc.x + bb.x); o.y = f2bf(acc.y + bb.y);
    o.z = f2bf(acc.z + bb.z); o.w = f2bf(acc.w + bb.w);
    *(ushort4*)(out1 + (size_t)d * F1 + lane * 4) = o;
}

// agg2 over h3 = h2 @ Wo; writes FINAL fp32 out with bc = b2@Wo + bo.
__global__ __launch_bounds__(256) void k_agg2(
    const int* __restrict__ offsets, const int* __restrict__ srcs,
    const ushort* __restrict__ h3, const float* __restrict__ a2s,
    const float* __restrict__ a2d, const float* __restrict__ bc,
    float* __restrict__ out) {
    __shared__ float atab[4][128];
    __shared__ int   stab[4][128];
    const int w = threadIdx.x >> 6;
    const int d = blockIdx.x * 4 + w;
    if (d >= NN) return;
    const int lane = threadIdx.x & 63;
    const int beg = offsets[d], end = offsets[d + 1];
    const int deg = end - beg;
    const float ad = a2d[d];
    float2 acc = make_float2(0.f, 0.f);

    if (deg <= 128) {
        float m = -1e30f, den = 0.f;
        for (int e = lane; e < deg; e += 64) {
            int s = srcs[beg + e];
            stab[w][e] = s;
            float v = lrelu(a2s[s] + ad);
            atab[w][e] = v;                    // raw logit
            float nm = fmaxf(m, v);
            den = den * __expf(m - nm) + __expf(v - nm);
            m = nm;
        }
        #pragma unroll
        for (int mask = 1; mask < 64; mask <<= 1) {
            float om = __shfl_xor(m, mask);
            float od = __shfl_xor(den, mask);
            float nm = fmaxf(m, om);
            den = den * __expf(m - nm) + od * __expf(om - nm);
            m = nm;
        }
        float rden = 1.f / (den + 1e-16f);
        for (int p = lane; p < deg; p += 64)
            atab[w][p] = __expf(atab[w][p] - m) * rden;
        int e = 0;
        for (; e + 8 <= deg; e += 8) {
            ushort2 u[8]; float a[8];
            #pragma unroll
            for (int jj = 0; jj < 8; ++jj) {
                int s = stab[w][e + jj];
                u[jj] = *(const ushort2*)(h3 + (size_t)s * F2 + lane * 2);
                a[jj] = atab[w][e + jj];
            }
            #pragma unroll
            for (int jj = 0; jj < 8; ++jj) {
                acc.x += a[jj] * bf2f(u[jj].x);
                acc.y += a[jj] * bf2f(u[jj].y);
            }
        }
        for (; e < deg; ++e) {
            int s = stab[w][e];
            float alpha = atab[w][e];
            ushort2 u = *(const ushort2*)(h3 + (size_t)s * F2 + lane * 2);
            acc.x += alpha * bf2f(u.x); acc.y += alpha * bf2f(u.y);
        }
    } else {
        float m = -1e30f, den = 0.f;
        for (int i = beg + lane; i < end; i += 64) {
            int s = srcs[i];
            float v = lrelu(a2s[s] + ad);
            float nm = fmaxf(m, v);
            den = den * __expf(m - nm) + __expf(v - nm);
            m = nm;
        }
        #pragma unroll
        for (int mask = 1; mask < 64; mask <<= 1) {
            float om = __shfl_xor(m, mask);
            float od = __shfl_xor(den, mask);
            float nm = fmaxf(m, om);
            den = den * __expf(m - nm) + od * __expf(om - nm);
            m = nm;
        }
        float rden = 1.f / (den + 1e-16f);
        for (int tb = beg; tb < end; tb += 64) {
            int cnt = min(64, end - tb);
            if (lane < cnt) {
                int s = srcs[tb + lane];
                stab[w][lane] = s;
                atab[w][lane] = __expf(lrelu(a2s[s] + ad) - m) * rden;
            }
            for (int e = 0; e < cnt; ++e) {
                int s = stab[w][e];
                float alpha = atab[w][e];
                ushort2 u = *(const ushort2*)(h3 + (size_t)s * F2 + lane * 2);
                acc.x += alpha * bf2f(u.x); acc.y += alpha * bf2f(u.y);
            }
        }
    }
    float2 bb = *(const float2*)(bc + lane * 2);
    *(float2*)(out + (size_t)d * F2 + lane * 2) = make_float2(acc.x + bb.x, acc.y + bb.y);
}

extern "C" void kernel_launch(void* const* d_in, const int* in_sizes, int n_in,
                              void* d_out, int out_size, void* d_ws, size_t ws_size,
                              hipStream_t stream) {
    const int*   x      = (const int*)d_in[0];
    const int*   edge   = (const int*)d_in[1];   // [2][E]
    const float* emb    = (const float*)d_in[2];
    const float* W1     = (const float*)d_in[3];
    const float* a_src1 = (const float*)d_in[4];
    const float* a_dst1 = (const float*)d_in[5];
    const float* b1     = (const float*)d_in[6];
    const float* W2     = (const float*)d_in[7];
    const float* a_src2 = (const float*)d_in[8];
    const float* a_dst2 = (const float*)d_in[9];
    const float* b2     = (const float*)d_in[10];
    const float* Wo     = (const float*)d_in[11];
    const float* bo     = (const float*)d_in[12];
    float* out = (float*)d_out;

    char* w = (char*)d_ws;
    auto alloc = [&](size_t bytes) {
        char* p = w;
        w += (bytes + 255) & ~(size_t)255;
        return p;
    };
    int*    offsets = (int*)alloc((NN + 1) * sizeof(int));
    int*    cursor  = (int*)alloc(NN * sizeof(int));
    int*    sums    = (int*)alloc(256 * sizeof(int));
    int*    srcs    = (int*)alloc((size_t)(EE + NN) * sizeof(int));
    ushort* Ax      = (ushort*)alloc((size_t)NN * DD * sizeof(ushort));
    ushort* W1t     = (ushort*)alloc((size_t)DD * F1 * sizeof(ushort));
    ushort* W2t     = (ushort*)alloc((size_t)F1 * F2 * sizeof(ushort));
    ushort* Wot     = (ushort*)alloc((size_t)F2 * F2 * sizeof(ushort));
    ushort* h1      = (ushort*)alloc((size_t)NN * F1 * sizeof(ushort));
    ushort* out1    = (ushort*)alloc((size_t)NN * F1 * sizeof(ushort));
    ushort* h2      = (ushort*)alloc((size_t)NN * F2 * sizeof(ushort));
    ushort* h3      = (ushort*)alloc((size_t)NN * F2 * sizeof(ushort));
    float*  a1s     = (float*)alloc((size_t)NN * 8 * sizeof(float));
    float*  a1d     = (float*)alloc((size_t)NN * 8 * sizeof(float));
    float*  bc      = (float*)alloc(F2 * sizeof(float));
    float*  a2s     = a1s;
    float*  a2d     = a1d;

    const int* esrc = edge;
    const int* edst = edge + EE;

    const int NB = (NN + 255) / 256;        // 196

    // CSR build + converts
    hipMemsetAsync(cursor, 0, NN * sizeof(int), stream);
    k_prep<<<HB + GB + W1B + W2B + WOB + 1, 256, 0, stream>>>(
        edst, cursor, x, emb, Ax, W1, W1t, W2, W2t, Wo, Wot, b2, bo, bc);
    k_scan1<<<NB, 256, 0, stream>>>(cursor, offsets, sums);
    k_scan3<<<NB, 256, 0, stream>>>(offsets, sums, cursor, NB);
    k_scatter<<<(EE + NN + 255) / 256, 256, 0, stream>>>(esrc, edst, cursor, srcs);

    const int MT = (NN + 127) / 128;        // 391

    // conv1 (GEMM + fused al1)
    k_mfma_gemm<DD, 1><<<dim3(MT, F1 / 128), 256, 0, stream>>>(
        Ax, W1t, h1, F1, nullptr, a_src1, a_dst1, a1s, a1d);
    k_agg1<<<(NN + 3) / 4, 256, 0, stream>>>(offsets, srcs, h1, a1s, a1d, b1, out1);

    // conv2 (GEMM + fused al2)
    k_mfma_gemm<F1, 2><<<dim3(MT, 1), 256, 0, stream>>>(
        out1, W2t, h2, F2, nullptr, a_src2, a_dst2, a2s, a2d);

    // h3 = h2 @ Wo (bf16)
    k_mfma_gemm<F2, 0><<<dim3(MT, 1), 256, 0, stream>>>(
        h2, Wot, h3, F2, nullptr, nullptr, nullptr, nullptr, nullptr);

    // final aggregation writes fp32 out directly
    k_agg2<<<(NN + 3) / 4, 256, 0, stream>>>(offsets, srcs, h3, a2s, a2d, bc, out);
}

// Round 8
// 357.574 us; speedup vs baseline: 1.0327x; 1.0186x over previous
//
#include <hip/hip_runtime.h>
#include <hip/hip_bf16.h>

#define NN 50000
#define EE 800000
#define DD 128
#define F1 256   // H*HID after conv1
#define F2 128   // OUT

using short8  = __attribute__((ext_vector_type(8))) short;
using floatx4 = __attribute__((ext_vector_type(4))) float;

__device__ inline float bf2f(ushort u) { return __uint_as_float(((unsigned)u) << 16); }
__device__ inline ushort f2bf(float f) {
    unsigned u = __float_as_uint(f);
    u += 0x7fffu + ((u >> 16) & 1u);      // round-to-nearest-even
    return (ushort)(u >> 16);
}

// ---------------- fused prep: hist + emb gather + weight transposes + bc ----------------
#define HB ((EE + 255) / 256)          // 3125
#define GB ((NN + 1) / 2)              // 25000
#define W1B ((DD * F1 + 255) / 256)    // 128
#define W2B ((F1 * F2 + 255) / 256)    // 128
#define WOB ((F2 * F2 + 255) / 256)    // 64

__global__ __launch_bounds__(256) void k_prep(
    const int* __restrict__ edst, int* __restrict__ cnt,
    const int* __restrict__ x, const float* __restrict__ emb, ushort* __restrict__ Ax,
    const float* __restrict__ W1, ushort* __restrict__ W1t,
    const float* __restrict__ W2, ushort* __restrict__ W2t,
    const float* __restrict__ Wo, ushort* __restrict__ Wot,
    const float* __restrict__ b2, const float* __restrict__ bo,
    float* __restrict__ bc) {
    int b = blockIdx.x;
    if (b < HB) {
        int i = b * 256 + threadIdx.x;
        if (i < EE) atomicAdd(&cnt[edst[i]], 1);
    } else if (b < HB + GB) {
        int row = (b - HB) * 2 + (threadIdx.x >> 7);
        if (row < NN) {
            int c = threadIdx.x & 127;
            Ax[(size_t)row * DD + c] = f2bf(emb[(size_t)x[row] * DD + c]);
        }
    } else if (b < HB + GB + W1B) {
        int idx = (b - HB - GB) * 256 + threadIdx.x;
        int k = idx / F1, n = idx % F1;
        W1t[(size_t)n * DD + k] = f2bf(W1[(size_t)k * F1 + n]);
    } else if (b < HB + GB + W1B + W2B) {
        int idx = (b - HB - GB - W1B) * 256 + threadIdx.x;
        int k = idx / F2, n = idx % F2;
        W2t[(size_t)n * F1 + k] = f2bf(W2[(size_t)k * F2 + n]);
    } else if (b < HB + GB + W1B + W2B + WOB) {
        int idx = (b - HB - GB - W1B - W2B) * 256 + threadIdx.x;
        int k = idx / F2, n = idx % F2;
        Wot[(size_t)n * F2 + k] = f2bf(Wo[(size_t)k * F2 + n]);
    } else {
        int j = threadIdx.x;
        if (j < F2) {
            float s = bo[j];
            for (int k = 0; k < F2; ++k) s += b2[k] * Wo[(size_t)k * F2 + j];
            bc[j] = s;
        }
    }
}

// ---------------- CSR scan + scatter ----------------
__global__ void k_scan1(const int* __restrict__ cnt, int* __restrict__ out,
                        int* __restrict__ sums) {
    __shared__ int s[256];
    int i = blockIdx.x * 256 + threadIdx.x;
    int v = (i < NN) ? cnt[i] + 1 : 0;   // +1 self-loop
    s[threadIdx.x] = v;
    __syncthreads();
    for (int off = 1; off < 256; off <<= 1) {
        int t = (threadIdx.x >= off) ? s[threadIdx.x - off] : 0;
        __syncthreads();
        s[threadIdx.x] += t;
        __syncthreads();
    }
    if (i < NN) out[i] = s[threadIdx.x] - v;   // exclusive
    if (threadIdx.x == 255) sums[blockIdx.x] = s[255];
}

__global__ void k_scan3(int* __restrict__ offsets, const int* __restrict__ sums,
                        int* __restrict__ cursor, int nb) {
    __shared__ int s[256];
    int v = (threadIdx.x < nb) ? sums[threadIdx.x] : 0;
    s[threadIdx.x] = v;
    __syncthreads();
    for (int off = 1; off < 256; off <<= 1) {
        int t = (threadIdx.x >= off) ? s[threadIdx.x - off] : 0;
        __syncthreads();
        s[threadIdx.x] += t;
        __syncthreads();
    }
    int base = (blockIdx.x == 0) ? 0 : s[blockIdx.x - 1];
    int i = blockIdx.x * 256 + threadIdx.x;
    if (i < NN) {
        int o = offsets[i] + base;
        offsets[i] = o;
        cursor[i] = o;
    }
    if (blockIdx.x == 0 && threadIdx.x == 0) offsets[NN] = EE + NN;
}

__global__ void k_scatter(const int* __restrict__ esrc, const int* __restrict__ edst,
                          int* __restrict__ cursor, int* __restrict__ srcs) {
    int i = blockIdx.x * 256 + threadIdx.x;
    if (i < EE) {
        int pos = atomicAdd(&cursor[edst[i]], 1);
        srcs[pos] = esrc[i];
    } else if (i < EE + NN) {
        int n = i - EE;
        int pos = atomicAdd(&cursor[n], 1);
        srcs[pos] = n;
    }
}

// ---------------- conv1 GEMM (128x128 tile) + fused 8-head attention logits ----------------
__global__ __launch_bounds__(256, 2) void k_gemm1(
    const ushort* __restrict__ A, const ushort* __restrict__ Bt,
    ushort* __restrict__ Cout,
    const float* __restrict__ avs, const float* __restrict__ avd,
    float* __restrict__ out_s, float* __restrict__ out_d) {
    __shared__ ushort As[128][72];   // [m][k]
    __shared__ ushort Bs[128][72];   // [n][k]
    const int t    = threadIdx.x;
    const int lane = t & 63;
    const int w    = t >> 6;
    const int wr   = w >> 1, wc = w & 1;
    const int m0   = blockIdx.x * 128;
    const int n0   = blockIdx.y * 128;
    floatx4 acc[4][4] = {};
    for (int k0 = 0; k0 < DD; k0 += 64) {
        #pragma unroll
        for (int p = 0; p < 4; ++p) {
            int linear = p * 2048 + t * 8;
            int row = linear >> 6;
            int col = linear & 63;
            short8 va = {};
            int gm = m0 + row;
            if (gm < NN) va = *(const short8*)(A + (size_t)gm * DD + k0 + col);
            *(short8*)&As[row][col] = va;
            short8 vb = *(const short8*)(Bt + (size_t)(n0 + row) * DD + k0 + col);
            *(short8*)&Bs[row][col] = vb;
        }
        __syncthreads();
        #pragma unroll
        for (int kk = 0; kk < 64; kk += 32) {
            const int q8 = (lane >> 4) * 8;
            short8 af[4], bf[4];
            #pragma unroll
            for (int i = 0; i < 4; ++i)
                af[i] = *(const short8*)&As[wr * 64 + i * 16 + (lane & 15)][kk + q8];
            #pragma unroll
            for (int j = 0; j < 4; ++j)
                bf[j] = *(const short8*)&Bs[wc * 64 + j * 16 + (lane & 15)][kk + q8];
            #pragma unroll
            for (int i = 0; i < 4; ++i)
                #pragma unroll
                for (int j = 0; j < 4; ++j)
                    acc[i][j] = __builtin_amdgcn_mfma_f32_16x16x32_bf16(
                        af[i], bf[j], acc[i][j], 0, 0, 0);
        }
        __syncthreads();
    }
    const int r0 = (lane >> 4) * 4;
    const int cc = lane & 15;
    float as0 = avs[n0 + wc * 64 +  0 + cc], ad0 = avd[n0 + wc * 64 +  0 + cc];
    float as1 = avs[n0 + wc * 64 + 16 + cc], ad1 = avd[n0 + wc * 64 + 16 + cc];
    float as2 = avs[n0 + wc * 64 + 32 + cc], ad2 = avd[n0 + wc * 64 + 32 + cc];
    float as3 = avs[n0 + wc * 64 + 48 + cc], ad3 = avd[n0 + wc * 64 + 48 + cc];
    #pragma unroll
    for (int i = 0; i < 4; ++i) {
        #pragma unroll
        for (int r = 0; r < 4; ++r) {
            int m = m0 + wr * 64 + i * 16 + r0 + r;
            float hs0 = acc[i][0][r] * as0 + acc[i][1][r] * as1;
            float hs1 = acc[i][2][r] * as2 + acc[i][3][r] * as3;
            float hd0 = acc[i][0][r] * ad0 + acc[i][1][r] * ad1;
            float hd1 = acc[i][2][r] * ad2 + acc[i][3][r] * ad3;
            #pragma unroll
            for (int mask = 1; mask < 16; mask <<= 1) {
                hs0 += __shfl_xor(hs0, mask);
                hs1 += __shfl_xor(hs1, mask);
                hd0 += __shfl_xor(hd0, mask);
                hd1 += __shfl_xor(hd1, mask);
            }
            if (cc == 0 && m < NN) {
                int gh = (n0 >> 5) + wc * 2;
                out_s[m * 8 + gh] = hs0;   out_s[m * 8 + gh + 1] = hs1;
                out_d[m * 8 + gh] = hd0;   out_d[m * 8 + gh + 1] = hd1;
            }
            if (m < NN) {
                #pragma unroll
                for (int j = 0; j < 4; ++j)
                    Cout[(size_t)m * F1 + n0 + wc * 64 + j * 16 + cc] = f2bf(acc[i][j][r]);
            }
        }
    }
}

// ---------------- fused conv2 GEMM + al2 + output-linear: h3 = (out1@W2)@Wo ----------------
// One block = 128 full rows. Phase 1: h2 = out1@W2 (K=256) + logits from fp32 acc.
// Phase 2: round h2 to bf16 in LDS, stage Wot, second MFMA pass, write h3 only.
__global__ __launch_bounds__(256, 2) void k_gemm23(
    const ushort* __restrict__ A,    // out1 [NN][F1]
    const ushort* __restrict__ Bt,   // W2t  [F2][F1]
    const ushort* __restrict__ Wot,  // [F2][F2] (pre-transposed [n][k])
    ushort* __restrict__ h3,         // [NN][F2]
    const float* __restrict__ avs, const float* __restrict__ avd,
    float* __restrict__ out_s, float* __restrict__ out_d) {
    __shared__ __align__(16) char smem[69632];
    ushort (*As)[72]   = (ushort(*)[72])smem;              // [128][72]
    ushort (*Bs)[72]   = (ushort(*)[72])(smem + 18432);    // [128][72]
    ushort (*h2t)[136] = (ushort(*)[136])smem;             // [128][136]
    ushort (*Wt)[136]  = (ushort(*)[136])(smem + 34816);   // [128][136]
    __shared__ float als[2][128], ald[2][128];
    const int t    = threadIdx.x;
    const int lane = t & 63;
    const int w    = t >> 6;
    const int wr   = w >> 1, wc = w & 1;
    const int m0   = blockIdx.x * 128;
    floatx4 acc[4][4] = {};
    for (int k0 = 0; k0 < F1; k0 += 64) {
        #pragma unroll
        for (int p = 0; p < 4; ++p) {
            int linear = p * 2048 + t * 8;
            int row = linear >> 6;
            int col = linear & 63;
            short8 va = {};
            int gm = m0 + row;
            if (gm < NN) va = *(const short8*)(A + (size_t)gm * F1 + k0 + col);
            *(short8*)&As[row][col] = va;
            short8 vb = *(const short8*)(Bt + (size_t)row * F1 + k0 + col);
            *(short8*)&Bs[row][col] = vb;
        }
        __syncthreads();
        #pragma unroll
        for (int kk = 0; kk < 64; kk += 32) {
            const int q8 = (lane >> 4) * 8;
            short8 af[4], bf[4];
            #pragma unroll
            for (int i = 0; i < 4; ++i)
                af[i] = *(const short8*)&As[wr * 64 + i * 16 + (lane & 15)][kk + q8];
            #pragma unroll
            for (int j = 0; j < 4; ++j)
                bf[j] = *(const short8*)&Bs[wc * 64 + j * 16 + (lane & 15)][kk + q8];
            #pragma unroll
            for (int i = 0; i < 4; ++i)
                #pragma unroll
                for (int j = 0; j < 4; ++j)
                    acc[i][j] = __builtin_amdgcn_mfma_f32_16x16x32_bf16(
                        af[i], bf[j], acc[i][j], 0, 0, 0);
        }
        __syncthreads();
    }
    const int r0 = (lane >> 4) * 4;
    const int cc = lane & 15;
    // 1-head logits from fp32 h2
    {
        float as0 = avs[wc * 64 +  0 + cc], ad0 = avd[wc * 64 +  0 + cc];
        float as1 = avs[wc * 64 + 16 + cc], ad1 = avd[wc * 64 + 16 + cc];
        float as2 = avs[wc * 64 + 32 + cc], ad2 = avd[wc * 64 + 32 + cc];
        float as3 = avs[wc * 64 + 48 + cc], ad3 = avd[wc * 64 + 48 + cc];
        #pragma unroll
        for (int i = 0; i < 4; ++i) {
            #pragma unroll
            for (int r = 0; r < 4; ++r) {
                float ps = acc[i][0][r] * as0 + acc[i][1][r] * as1
                         + acc[i][2][r] * as2 + acc[i][3][r] * as3;
                float pd = acc[i][0][r] * ad0 + acc[i][1][r] * ad1
                         + acc[i][2][r] * ad2 + acc[i][3][r] * ad3;
                #pragma unroll
                for (int mask = 1; mask < 16; mask <<= 1) {
                    ps += __shfl_xor(ps, mask);
                    pd += __shfl_xor(pd, mask);
                }
                if (cc == 0) {
                    int lr = wr * 64 + i * 16 + r0 + r;
                    als[wc][lr] = ps;
                    ald[wc][lr] = pd;
                }
            }
        }
    }
    // round h2 -> bf16 into LDS (unions over As/Bs; all reads of As/Bs are done)
    #pragma unroll
    for (int i = 0; i < 4; ++i)
        #pragma unroll
        for (int r = 0; r < 4; ++r)
            #pragma unroll
            for (int j = 0; j < 4; ++j)
                h2t[wr * 64 + i * 16 + r0 + r][wc * 64 + j * 16 + cc] = f2bf(acc[i][j][r]);
    // stage Wot [128][128]
    #pragma unroll
    for (int p = 0; p < 8; ++p) {
        int linear = p * 2048 + t * 8;
        int row = linear >> 7;
        int col = linear & 127;
        *(short8*)&Wt[row][col] = *(const short8*)(Wot + (size_t)row * F2 + col);
    }
    __syncthreads();
    // logits combine
    if (t < 128) {
        int m = m0 + t;
        if (m < NN) {
            out_s[m] = als[0][t] + als[1][t];
            out_d[m] = ald[0][t] + ald[1][t];
        }
    }
    // phase 2: h3 = h2t @ Wt^T  (K = 128)
    floatx4 acc2[4][4] = {};
    #pragma unroll
    for (int kk = 0; kk < 128; kk += 32) {
        const int q8 = (lane >> 4) * 8;
        short8 af[4], bf[4];
        #pragma unroll
        for (int i = 0; i < 4; ++i)
            af[i] = *(const short8*)&h2t[wr * 64 + i * 16 + (lane & 15)][kk + q8];
        #pragma unroll
        for (int j = 0; j < 4; ++j)
            bf[j] = *(const short8*)&Wt[wc * 64 + j * 16 + (lane & 15)][kk + q8];
        #pragma unroll
        for (int i = 0; i < 4; ++i)
            #pragma unroll
            for (int j = 0; j < 4; ++j)
                acc2[i][j] = __builtin_amdgcn_mfma_f32_16x16x32_bf16(
                    af[i], bf[j], acc2[i][j], 0, 0, 0);
    }
    #pragma unroll
    for (int i = 0; i < 4; ++i) {
        #pragma unroll
        for (int r = 0; r < 4; ++r) {
            int m = m0 + wr * 64 + i * 16 + r0 + r;
            if (m < NN) {
                #pragma unroll
                for (int j = 0; j < 4; ++j)
                    h3[(size_t)m * F2 + wc * 64 + j * 16 + cc] = f2bf(acc2[i][j][r]);
            }
        }
    }
}

__device__ inline float lrelu(float x) { return x > 0.f ? x : 0.2f * x; }

// ---------------- GAT aggregation ----------------
// Fast path (deg <= 64): single load pass caches src+raw logits in LDS; LDS-only
// normalize; channel gather. Slow path (rare) = 3-pass 64-edge tiles.
__global__ __launch_bounds__(256) void k_agg1(
    const int* __restrict__ offsets, const int* __restrict__ srcs,
    const ushort* __restrict__ h1, const float* __restrict__ a1s,
    const float* __restrict__ a1d, const float* __restrict__ b1,
    ushort* __restrict__ out1) {
    __shared__ float atab[4][512];   // [wave][edge*8+head], deg<=64
    __shared__ int   stab[4][64];
    const int w = threadIdx.x >> 6;
    const int d = blockIdx.x * 4 + w;
    if (d >= NN) return;
    const int lane = threadIdx.x & 63;
    const int beg = offsets[d], end = offsets[d + 1];
    const int deg = end - beg;
    const int e8 = lane >> 3, h8 = lane & 7;
    const float ad = a1d[d * 8 + h8];
    const int hh = lane >> 3;
    float4 acc = make_float4(0.f, 0.f, 0.f, 0.f);

    if (deg <= 64) {
        float m = -1e30f, den = 0.f;
        for (int e = e8; e < deg; e += 8) {
            int s = srcs[beg + e];
            if (h8 == 0) stab[w][e] = s;
            float v = lrelu(a1s[s * 8 + h8] + ad);
            atab[w][e * 8 + h8] = v;            // raw logit
            float nm = fmaxf(m, v);
            den = den * __expf(m - nm) + __expf(v - nm);
            m = nm;
        }
        #pragma unroll
        for (int mask = 8; mask < 64; mask <<= 1) {
            float om = __shfl_xor(m, mask);
            float od = __shfl_xor(den, mask);
            float nm = fmaxf(m, om);
            den = den * __expf(m - nm) + od * __expf(om - nm);
            m = nm;
        }
        float rden = 1.f / (den + 1e-16f);
        for (int p = lane; p < deg * 8; p += 64)    // p&7 == h8
            atab[w][p] = __expf(atab[w][p] - m) * rden;
        int e = 0;
        for (; e + 8 <= deg; e += 8) {
            ushort4 u[8]; float a[8];
            #pragma unroll
            for (int jj = 0; jj < 8; ++jj) {
                int s = stab[w][e + jj];
                u[jj] = *(const ushort4*)(h1 + (size_t)s * F1 + lane * 4);
                a[jj] = atab[w][(e + jj) * 8 + hh];
            }
            #pragma unroll
            for (int jj = 0; jj < 8; ++jj) {
                acc.x += a[jj] * bf2f(u[jj].x);
                acc.y += a[jj] * bf2f(u[jj].y);
                acc.z += a[jj] * bf2f(u[jj].z);
                acc.w += a[jj] * bf2f(u[jj].w);
            }
        }
        for (; e < deg; ++e) {
            int s = stab[w][e];
            float alpha = atab[w][e * 8 + hh];
            ushort4 u = *(const ushort4*)(h1 + (size_t)s * F1 + lane * 4);
            acc.x += alpha * bf2f(u.x); acc.y += alpha * bf2f(u.y);
            acc.z += alpha * bf2f(u.z); acc.w += alpha * bf2f(u.w);
        }
    } else {
        float m = -1e30f, den = 0.f;
        for (int i = beg + e8; i < end; i += 8) {
            int s = srcs[i];
            float v = lrelu(a1s[s * 8 + h8] + ad);
            float nm = fmaxf(m, v);
            den = den * __expf(m - nm) + __expf(v - nm);
            m = nm;
        }
        #pragma unroll
        for (int mask = 8; mask < 64; mask <<= 1) {
            float om = __shfl_xor(m, mask);
            float od = __shfl_xor(den, mask);
            float nm = fmaxf(m, om);
            den = den * __expf(m - nm) + od * __expf(om - nm);
            m = nm;
        }
        float rden = 1.f / (den + 1e-16f);
        for (int tb = beg; tb < end; tb += 64) {
            int cnt = min(64, end - tb);
            if (lane < cnt) stab[w][lane] = srcs[tb + lane];
            int np = cnt * 8;
            for (int p = lane; p < np; p += 64) {
                int s = stab[w][p >> 3];
                float v = lrelu(a1s[s * 8 + h8] + ad);
                atab[w][p] = __expf(v - m) * rden;
            }
            for (int e = 0; e < cnt; ++e) {
                int s = stab[w][e];
                float alpha = atab[w][e * 8 + hh];
                ushort4 u = *(const ushort4*)(h1 + (size_t)s * F1 + lane * 4);
                acc.x += alpha * bf2f(u.x); acc.y += alpha * bf2f(u.y);
                acc.z += alpha * bf2f(u.z); acc.w += alpha * bf2f(u.w);
            }
        }
    }
    float4 bb = *(const float4*)(b1 + lane * 4);
    ushort4 o;
    o.x = f2bf(acc.x + bb.x); o.y = f2bf(acc.y + bb.y);
    o.z = f2bf(acc.z + bb.z); o.w = f2bf(acc.w + bb.w);
    *(ushort4*)(out1 + (size_t)d * F1 + lane * 4) = o;
}

// agg2 over h3 = (h2)@Wo; writes FINAL fp32 out with bc = b2@Wo + bo.
__global__ __launch_bounds__(256) void k_agg2(
    const int* __restrict__ offsets, const int* __restrict__ srcs,
    const ushort* __restrict__ h3, const float* __restrict__ a2s,
    const float* __restrict__ a2d, const float* __restrict__ bc,
    float* __restrict__ out) {
    __shared__ float atab[4][64];
    __shared__ int   stab[4][64];
    const int w = threadIdx.x >> 6;
    const int d = blockIdx.x * 4 + w;
    if (d >= NN) return;
    const int lane = threadIdx.x & 63;
    const int beg = offsets[d], end = offsets[d + 1];
    const int deg = end - beg;
    const float ad = a2d[d];
    float2 acc = make_float2(0.f, 0.f);

    if (deg <= 64) {
        float m = -1e30f, den = 0.f;
        if (lane < deg) {
            int s = srcs[beg + lane];
            stab[w][lane] = s;
            float v = lrelu(a2s[s] + ad);
            atab[w][lane] = v;
            m = v;
            den = 1.f;
        }
        #pragma unroll
        for (int mask = 1; mask < 64; mask <<= 1) {
            float om = __shfl_xor(m, mask);
            float od = __shfl_xor(den, mask);
            float nm = fmaxf(m, om);
            den = den * __expf(m - nm) + od * __expf(om - nm);
            m = nm;
        }
        float rden = 1.f / (den + 1e-16f);
        if (lane < deg)
            atab[w][lane] = __expf(atab[w][lane] - m) * rden;
        int e = 0;
        for (; e + 8 <= deg; e += 8) {
            ushort2 u[8]; float a[8];
            #pragma unroll
            for (int jj = 0; jj < 8; ++jj) {
                int s = stab[w][e + jj];
                u[jj] = *(const ushort2*)(h3 + (size_t)s * F2 + lane * 2);
                a[jj] = atab[w][e + jj];
            }
            #pragma unroll
            for (int jj = 0; jj < 8; ++jj) {
                acc.x += a[jj] * bf2f(u[jj].x);
                acc.y += a[jj] * bf2f(u[jj].y);
            }
        }
        for (; e < deg; ++e) {
            int s = stab[w][e];
            float alpha = atab[w][e];
            ushort2 u = *(const ushort2*)(h3 + (size_t)s * F2 + lane * 2);
            acc.x += alpha * bf2f(u.x); acc.y += alpha * bf2f(u.y);
        }
    } else {
        float m = -1e30f, den = 0.f;
        for (int i = beg + lane; i < end; i += 64) {
            int s = srcs[i];
            float v = lrelu(a2s[s] + ad);
            float nm = fmaxf(m, v);
            den = den * __expf(m - nm) + __expf(v - nm);
            m = nm;
        }
        #pragma unroll
        for (int mask = 1; mask < 64; mask <<= 1) {
            float om = __shfl_xor(m, mask);
            float od = __shfl_xor(den, mask);
            float nm = fmaxf(m, om);
            den = den * __expf(m - nm) + od * __expf(om - nm);
            m = nm;
        }
        float rden = 1.f / (den + 1e-16f);
        for (int tb = beg; tb < end; tb += 64) {
            int cnt = min(64, end - tb);
            if (lane < cnt) {
                int s = srcs[tb + lane];
                stab[w][lane] = s;
                atab[w][lane] = __expf(lrelu(a2s[s] + ad) - m) * rden;
            }
            for (int e = 0; e < cnt; ++e) {
                int s = stab[w][e];
                float alpha = atab[w][e];
                ushort2 u = *(const ushort2*)(h3 + (size_t)s * F2 + lane * 2);
                acc.x += alpha * bf2f(u.x); acc.y += alpha * bf2f(u.y);
            }
        }
    }
    float2 bb = *(const float2*)(bc + lane * 2);
    *(float2*)(out + (size_t)d * F2 + lane * 2) = make_float2(acc.x + bb.x, acc.y + bb.y);
}

extern "C" void kernel_launch(void* const* d_in, const int* in_sizes, int n_in,
                              void* d_out, int out_size, void* d_ws, size_t ws_size,
                              hipStream_t stream) {
    const int*   x      = (const int*)d_in[0];
    const int*   edge   = (const int*)d_in[1];   // [2][E]
    const float* emb    = (const float*)d_in[2];
    const float* W1     = (const float*)d_in[3];
    const float* a_src1 = (const float*)d_in[4];
    const float* a_dst1 = (const float*)d_in[5];
    const float* b1     = (const float*)d_in[6];
    const float* W2     = (const float*)d_in[7];
    const float* a_src2 = (const float*)d_in[8];
    const float* a_dst2 = (const float*)d_in[9];
    const float* b2     = (const float*)d_in[10];
    const float* Wo     = (const float*)d_in[11];
    const float* bo     = (const float*)d_in[12];
    float* out = (float*)d_out;

    char* w = (char*)d_ws;
    auto alloc = [&](size_t bytes) {
        char* p = w;
        w += (bytes + 255) & ~(size_t)255;
        return p;
    };
    int*    offsets = (int*)alloc((NN + 1) * sizeof(int));
    int*    cursor  = (int*)alloc(NN * sizeof(int));
    int*    sums    = (int*)alloc(256 * sizeof(int));
    int*    srcs    = (int*)alloc((size_t)(EE + NN) * sizeof(int));
    ushort* Ax      = (ushort*)alloc((size_t)NN * DD * sizeof(ushort));
    ushort* W1t     = (ushort*)alloc((size_t)DD * F1 * sizeof(ushort));
    ushort* W2t     = (ushort*)alloc((size_t)F1 * F2 * sizeof(ushort));
    ushort* Wot     = (ushort*)alloc((size_t)F2 * F2 * sizeof(ushort));
    ushort* h1      = (ushort*)alloc((size_t)NN * F1 * sizeof(ushort));
    ushort* out1    = (ushort*)alloc((size_t)NN * F1 * sizeof(ushort));
    ushort* h3      = (ushort*)alloc((size_t)NN * F2 * sizeof(ushort));
    float*  a1s     = (float*)alloc((size_t)NN * 8 * sizeof(float));
    float*  a1d     = (float*)alloc((size_t)NN * 8 * sizeof(float));
    float*  bc      = (float*)alloc(F2 * sizeof(float));
    float*  a2s     = a1s;
    float*  a2d     = a1d;

    const int* esrc = edge;
    const int* edst = edge + EE;

    const int NB = (NN + 255) / 256;        // 196

    // CSR build + converts
    hipMemsetAsync(cursor, 0, NN * sizeof(int), stream);
    k_prep<<<HB + GB + W1B + W2B + WOB + 1, 256, 0, stream>>>(
        edst, cursor, x, emb, Ax, W1, W1t, W2, W2t, Wo, Wot, b2, bo, bc);
    k_scan1<<<NB, 256, 0, stream>>>(cursor, offsets, sums);
    k_scan3<<<NB, 256, 0, stream>>>(offsets, sums, cursor, NB);
    k_scatter<<<(EE + NN + 255) / 256, 256, 0, stream>>>(esrc, edst, cursor, srcs);

    const int MT = (NN + 127) / 128;        // 391

    // conv1 (GEMM + fused al1)
    k_gemm1<<<dim3(MT, F1 / 128), 256, 0, stream>>>(
        Ax, W1t, h1, a_src1, a_dst1, a1s, a1d);
    k_agg1<<<(NN + 3) / 4, 256, 0, stream>>>(offsets, srcs, h1, a1s, a1d, b1, out1);

    // conv2 GEMM + al2 + output linear fused: h3 = (out1@W2)@Wo
    k_gemm23<<<dim3(MT, 1), 256, 0, stream>>>(
        out1, W2t, Wot, h3, a_src2, a_dst2, a2s, a2d);

    // final aggregation writes fp32 out directly
    k_agg2<<<(NN + 3) / 4, 256, 0, stream>>>(offsets, srcs, h3, a2s, a2d, bc, out);
}

// Round 9
// 346.940 us; speedup vs baseline: 1.0643x; 1.0307x over previous
//
#include <hip/hip_runtime.h>
#include <hip/hip_bf16.h>

#define NN 50000
#define EE 800000
#define DD 128
#define F1 256   // H*HID after conv1
#define F2 128   // OUT

using short8  = __attribute__((ext_vector_type(8))) short;
using floatx4 = __attribute__((ext_vector_type(4))) float;

__device__ inline float bf2f(ushort u) { return __uint_as_float(((unsigned)u) << 16); }
__device__ inline ushort f2bf(float f) {
    unsigned u = __float_as_uint(f);
    u += 0x7fffu + ((u >> 16) & 1u);      // round-to-nearest-even
    return (ushort)(u >> 16);
}

// ---------------- fused prep: edge histogram + weight transposes + bc ----------------
#define HB ((EE + 255) / 256)          // 3125
#define W1B ((DD * F1 + 255) / 256)    // 128
#define W2B ((F1 * F2 + 255) / 256)    // 128
#define WOB ((F2 * F2 + 255) / 256)    // 64

__global__ __launch_bounds__(256) void k_prep(
    const int* __restrict__ edst, int* __restrict__ cnt,
    const float* __restrict__ W1, ushort* __restrict__ W1t,
    const float* __restrict__ W2, ushort* __restrict__ W2t,
    const float* __restrict__ Wo, ushort* __restrict__ Wot,
    const float* __restrict__ b2, const float* __restrict__ bo,
    float* __restrict__ bc) {
    int b = blockIdx.x;
    if (b < HB) {
        int i = b * 256 + threadIdx.x;
        if (i < EE) atomicAdd(&cnt[edst[i]], 1);
    } else if (b < HB + W1B) {
        int idx = (b - HB) * 256 + threadIdx.x;
        int k = idx / F1, n = idx % F1;
        W1t[(size_t)n * DD + k] = f2bf(W1[(size_t)k * F1 + n]);
    } else if (b < HB + W1B + W2B) {
        int idx = (b - HB - W1B) * 256 + threadIdx.x;
        int k = idx / F2, n = idx % F2;
        W2t[(size_t)n * F1 + k] = f2bf(W2[(size_t)k * F2 + n]);
    } else if (b < HB + W1B + W2B + WOB) {
        int idx = (b - HB - W1B - W2B) * 256 + threadIdx.x;
        int k = idx / F2, n = idx % F2;
        Wot[(size_t)n * F2 + k] = f2bf(Wo[(size_t)k * F2 + n]);
    } else {
        int j = threadIdx.x;
        if (j < F2) {
            float s = bo[j];
            for (int k = 0; k < F2; ++k) s += b2[k] * Wo[(size_t)k * F2 + j];
            bc[j] = s;
        }
    }
}

// ---------------- CSR scan + scatter ----------------
__global__ void k_scan1(const int* __restrict__ cnt, int* __restrict__ out,
                        int* __restrict__ sums) {
    __shared__ int s[256];
    int i = blockIdx.x * 256 + threadIdx.x;
    int v = (i < NN) ? cnt[i] + 1 : 0;   // +1 self-loop
    s[threadIdx.x] = v;
    __syncthreads();
    for (int off = 1; off < 256; off <<= 1) {
        int t = (threadIdx.x >= off) ? s[threadIdx.x - off] : 0;
        __syncthreads();
        s[threadIdx.x] += t;
        __syncthreads();
    }
    if (i < NN) out[i] = s[threadIdx.x] - v;   // exclusive
    if (threadIdx.x == 255) sums[blockIdx.x] = s[255];
}

__global__ void k_scan3(int* __restrict__ offsets, const int* __restrict__ sums,
                        int* __restrict__ cursor, int nb) {
    __shared__ int s[256];
    int v = (threadIdx.x < nb) ? sums[threadIdx.x] : 0;
    s[threadIdx.x] = v;
    __syncthreads();
    for (int off = 1; off < 256; off <<= 1) {
        int t = (threadIdx.x >= off) ? s[threadIdx.x - off] : 0;
        __syncthreads();
        s[threadIdx.x] += t;
        __syncthreads();
    }
    int base = (blockIdx.x == 0) ? 0 : s[blockIdx.x - 1];
    int i = blockIdx.x * 256 + threadIdx.x;
    if (i < NN) {
        int o = offsets[i] + base;
        offsets[i] = o;
        cursor[i] = o;
    }
    if (blockIdx.x == 0 && threadIdx.x == 0) offsets[NN] = EE + NN;
}

// edges via atomic cursor (fill offsets[n]..offsets[n+1]-2);
// self-loop deterministically at offsets[n+1]-1 (no atomic).
__global__ void k_scatter(const int* __restrict__ esrc, const int* __restrict__ edst,
                          const int* __restrict__ offsets,
                          int* __restrict__ cursor, int* __restrict__ srcs) {
    int i = blockIdx.x * 256 + threadIdx.x;
    if (i < EE) {
        int pos = atomicAdd(&cursor[edst[i]], 1);
        srcs[pos] = esrc[i];
    } else if (i < EE + NN) {
        int n = i - EE;
        srcs[offsets[n + 1] - 1] = n;
    }
}

// ---------------- conv1 GEMM (128x128 tile) + fused emb-gather + 8-head logits ----------------
__global__ __launch_bounds__(256, 2) void k_gemm1(
    const int* __restrict__ x, const float* __restrict__ emb,
    const ushort* __restrict__ Bt,
    ushort* __restrict__ Cout,
    const float* __restrict__ avs, const float* __restrict__ avd,
    float* __restrict__ out_s, float* __restrict__ out_d) {
    __shared__ ushort As[128][72];   // [m][k]
    __shared__ ushort Bs[128][72];   // [n][k]
    const int t    = threadIdx.x;
    const int lane = t & 63;
    const int w    = t >> 6;
    const int wr   = w >> 1, wc = w & 1;
    const int m0   = blockIdx.x * 128;
    const int n0   = blockIdx.y * 128;
    floatx4 acc[4][4] = {};
    for (int k0 = 0; k0 < DD; k0 += 64) {
        #pragma unroll
        for (int p = 0; p < 4; ++p) {
            int linear = p * 2048 + t * 8;
            int row = linear >> 6;
            int col = linear & 63;
            short8 va = {};
            int gm = m0 + row;
            if (gm < NN) {
                const float* er = emb + (size_t)x[gm] * DD + k0 + col;
                float4 f0 = *(const float4*)er;
                float4 f1 = *(const float4*)(er + 4);
                va[0] = f2bf(f0.x); va[1] = f2bf(f0.y);
                va[2] = f2bf(f0.z); va[3] = f2bf(f0.w);
                va[4] = f2bf(f1.x); va[5] = f2bf(f1.y);
                va[6] = f2bf(f1.z); va[7] = f2bf(f1.w);
            }
            *(short8*)&As[row][col] = va;
            short8 vb = *(const short8*)(Bt + (size_t)(n0 + row) * DD + k0 + col);
            *(short8*)&Bs[row][col] = vb;
        }
        __syncthreads();
        #pragma unroll
        for (int kk = 0; kk < 64; kk += 32) {
            const int q8 = (lane >> 4) * 8;
            short8 af[4], bf[4];
            #pragma unroll
            for (int i = 0; i < 4; ++i)
                af[i] = *(const short8*)&As[wr * 64 + i * 16 + (lane & 15)][kk + q8];
            #pragma unroll
            for (int j = 0; j < 4; ++j)
                bf[j] = *(const short8*)&Bs[wc * 64 + j * 16 + (lane & 15)][kk + q8];
            #pragma unroll
            for (int i = 0; i < 4; ++i)
                #pragma unroll
                for (int j = 0; j < 4; ++j)
                    acc[i][j] = __builtin_amdgcn_mfma_f32_16x16x32_bf16(
                        af[i], bf[j], acc[i][j], 0, 0, 0);
        }
        __syncthreads();
    }
    const int r0 = (lane >> 4) * 4;
    const int cc = lane & 15;
    float as0 = avs[n0 + wc * 64 +  0 + cc], ad0 = avd[n0 + wc * 64 +  0 + cc];
    float as1 = avs[n0 + wc * 64 + 16 + cc], ad1 = avd[n0 + wc * 64 + 16 + cc];
    float as2 = avs[n0 + wc * 64 + 32 + cc], ad2 = avd[n0 + wc * 64 + 32 + cc];
    float as3 = avs[n0 + wc * 64 + 48 + cc], ad3 = avd[n0 + wc * 64 + 48 + cc];
    #pragma unroll
    for (int i = 0; i < 4; ++i) {
        #pragma unroll
        for (int r = 0; r < 4; ++r) {
            int m = m0 + wr * 64 + i * 16 + r0 + r;
            float hs0 = acc[i][0][r] * as0 + acc[i][1][r] * as1;
            float hs1 = acc[i][2][r] * as2 + acc[i][3][r] * as3;
            float hd0 = acc[i][0][r] * ad0 + acc[i][1][r] * ad1;
            float hd1 = acc[i][2][r] * ad2 + acc[i][3][r] * ad3;
            #pragma unroll
            for (int mask = 1; mask < 16; mask <<= 1) {
                hs0 += __shfl_xor(hs0, mask);
                hs1 += __shfl_xor(hs1, mask);
                hd0 += __shfl_xor(hd0, mask);
                hd1 += __shfl_xor(hd1, mask);
            }
            if (cc == 0 && m < NN) {
                int gh = (n0 >> 5) + wc * 2;
                out_s[m * 8 + gh] = hs0;   out_s[m * 8 + gh + 1] = hs1;
                out_d[m * 8 + gh] = hd0;   out_d[m * 8 + gh + 1] = hd1;
            }
            if (m < NN) {
                #pragma unroll
                for (int j = 0; j < 4; ++j)
                    Cout[(size_t)m * F1 + n0 + wc * 64 + j * 16 + cc] = f2bf(acc[i][j][r]);
            }
        }
    }
}

// ---------------- fused conv2 GEMM + al2 + output-linear: h3 = (out1@W2)@Wo ----------------
__global__ __launch_bounds__(256, 2) void k_gemm23(
    const ushort* __restrict__ A,    // out1 [NN][F1]
    const ushort* __restrict__ Bt,   // W2t  [F2][F1]
    const ushort* __restrict__ Wot,  // [F2][F2] (pre-transposed [n][k])
    ushort* __restrict__ h3,         // [NN][F2]
    const float* __restrict__ avs, const float* __restrict__ avd,
    float* __restrict__ out_s, float* __restrict__ out_d) {
    __shared__ __align__(16) char smem[69632];
    ushort (*As)[72]   = (ushort(*)[72])smem;              // [128][72]
    ushort (*Bs)[72]   = (ushort(*)[72])(smem + 18432);    // [128][72]
    ushort (*h2t)[136] = (ushort(*)[136])smem;             // [128][136]
    ushort (*Wt)[136]  = (ushort(*)[136])(smem + 34816);   // [128][136]
    __shared__ float als[2][128], ald[2][128];
    const int t    = threadIdx.x;
    const int lane = t & 63;
    const int w    = t >> 6;
    const int wr   = w >> 1, wc = w & 1;
    const int m0   = blockIdx.x * 128;
    floatx4 acc[4][4] = {};
    for (int k0 = 0; k0 < F1; k0 += 64) {
        #pragma unroll
        for (int p = 0; p < 4; ++p) {
            int linear = p * 2048 + t * 8;
            int row = linear >> 6;
            int col = linear & 63;
            short8 va = {};
            int gm = m0 + row;
            if (gm < NN) va = *(const short8*)(A + (size_t)gm * F1 + k0 + col);
            *(short8*)&As[row][col] = va;
            short8 vb = *(const short8*)(Bt + (size_t)row * F1 + k0 + col);
            *(short8*)&Bs[row][col] = vb;
        }
        __syncthreads();
        #pragma unroll
        for (int kk = 0; kk < 64; kk += 32) {
            const int q8 = (lane >> 4) * 8;
            short8 af[4], bf[4];
            #pragma unroll
            for (int i = 0; i < 4; ++i)
                af[i] = *(const short8*)&As[wr * 64 + i * 16 + (lane & 15)][kk + q8];
            #pragma unroll
            for (int j = 0; j < 4; ++j)
                bf[j] = *(const short8*)&Bs[wc * 64 + j * 16 + (lane & 15)][kk + q8];
            #pragma unroll
            for (int i = 0; i < 4; ++i)
                #pragma unroll
                for (int j = 0; j < 4; ++j)
                    acc[i][j] = __builtin_amdgcn_mfma_f32_16x16x32_bf16(
                        af[i], bf[j], acc[i][j], 0, 0, 0);
        }
        __syncthreads();
    }
    const int r0 = (lane >> 4) * 4;
    const int cc = lane & 15;
    // 1-head logits from fp32 h2
    {
        float as0 = avs[wc * 64 +  0 + cc], ad0 = avd[wc * 64 +  0 + cc];
        float as1 = avs[wc * 64 + 16 + cc], ad1 = avd[wc * 64 + 16 + cc];
        float as2 = avs[wc * 64 + 32 + cc], ad2 = avd[wc * 64 + 32 + cc];
        float as3 = avs[wc * 64 + 48 + cc], ad3 = avd[wc * 64 + 48 + cc];
        #pragma unroll
        for (int i = 0; i < 4; ++i) {
            #pragma unroll
            for (int r = 0; r < 4; ++r) {
                float ps = acc[i][0][r] * as0 + acc[i][1][r] * as1
                         + acc[i][2][r] * as2 + acc[i][3][r] * as3;
                float pd = acc[i][0][r] * ad0 + acc[i][1][r] * ad1
                         + acc[i][2][r] * ad2 + acc[i][3][r] * ad3;
                #pragma unroll
                for (int mask = 1; mask < 16; mask <<= 1) {
                    ps += __shfl_xor(ps, mask);
                    pd += __shfl_xor(pd, mask);
                }
                if (cc == 0) {
                    int lr = wr * 64 + i * 16 + r0 + r;
                    als[wc][lr] = ps;
                    ald[wc][lr] = pd;
                }
            }
        }
    }
    // round h2 -> bf16 into LDS (unions over As/Bs; all reads of As/Bs done)
    #pragma unroll
    for (int i = 0; i < 4; ++i)
        #pragma unroll
        for (int r = 0; r < 4; ++r)
            #pragma unroll
            for (int j = 0; j < 4; ++j)
                h2t[wr * 64 + i * 16 + r0 + r][wc * 64 + j * 16 + cc] = f2bf(acc[i][j][r]);
    // stage Wot [128][128]
    #pragma unroll
    for (int p = 0; p < 8; ++p) {
        int linear = p * 2048 + t * 8;
        int row = linear >> 7;
        int col = linear & 127;
        *(short8*)&Wt[row][col] = *(const short8*)(Wot + (size_t)row * F2 + col);
    }
    __syncthreads();
    if (t < 128) {
        int m = m0 + t;
        if (m < NN) {
            out_s[m] = als[0][t] + als[1][t];
            out_d[m] = ald[0][t] + ald[1][t];
        }
    }
    // phase 2: h3 = h2t @ Wt^T  (K = 128)
    floatx4 acc2[4][4] = {};
    #pragma unroll
    for (int kk = 0; kk < 128; kk += 32) {
        const int q8 = (lane >> 4) * 8;
        short8 af[4], bf[4];
        #pragma unroll
        for (int i = 0; i < 4; ++i)
            af[i] = *(const short8*)&h2t[wr * 64 + i * 16 + (lane & 15)][kk + q8];
        #pragma unroll
        for (int j = 0; j < 4; ++j)
            bf[j] = *(const short8*)&Wt[wc * 64 + j * 16 + (lane & 15)][kk + q8];
        #pragma unroll
        for (int i = 0; i < 4; ++i)
            #pragma unroll
            for (int j = 0; j < 4; ++j)
                acc2[i][j] = __builtin_amdgcn_mfma_f32_16x16x32_bf16(
                    af[i], bf[j], acc2[i][j], 0, 0, 0);
    }
    #pragma unroll
    for (int i = 0; i < 4; ++i) {
        #pragma unroll
        for (int r = 0; r < 4; ++r) {
            int m = m0 + wr * 64 + i * 16 + r0 + r;
            if (m < NN) {
                #pragma unroll
                for (int j = 0; j < 4; ++j)
                    h3[(size_t)m * F2 + wc * 64 + j * 16 + cc] = f2bf(acc2[i][j][r]);
            }
        }
    }
}

__device__ inline float lrelu(float x) { return x > 0.f ? x : 0.2f * x; }

// ---------------- GAT aggregation ----------------
__global__ __launch_bounds__(256) void k_agg1(
    const int* __restrict__ offsets, const int* __restrict__ srcs,
    const ushort* __restrict__ h1, const float* __restrict__ a1s,
    const float* __restrict__ a1d, const float* __restrict__ b1,
    ushort* __restrict__ out1) {
    __shared__ float atab[4][512];   // [wave][edge*8+head], deg<=64
    __shared__ int   stab[4][64];
    const int w = threadIdx.x >> 6;
    const int d = blockIdx.x * 4 + w;
    if (d >= NN) return;
    const int lane = threadIdx.x & 63;
    const int beg = offsets[d], end = offsets[d + 1];
    const int deg = end - beg;
    const int e8 = lane >> 3, h8 = lane & 7;
    const float ad = a1d[d * 8 + h8];
    const int hh = lane >> 3;
    float4 acc = make_float4(0.f, 0.f, 0.f, 0.f);

    if (deg <= 64) {
        float m = -1e30f, den = 0.f;
        for (int e = e8; e < deg; e += 8) {
            int s = srcs[beg + e];
            if (h8 == 0) stab[w][e] = s;
            float v = lrelu(a1s[s * 8 + h8] + ad);
            atab[w][e * 8 + h8] = v;            // raw logit
            float nm = fmaxf(m, v);
            den = den * __expf(m - nm) + __expf(v - nm);
            m = nm;
        }
        #pragma unroll
        for (int mask = 8; mask < 64; mask <<= 1) {
            float om = __shfl_xor(m, mask);
            float od = __shfl_xor(den, mask);
            float nm = fmaxf(m, om);
            den = den * __expf(m - nm) + od * __expf(om - nm);
            m = nm;
        }
        float rden = 1.f / (den + 1e-16f);
        for (int p = lane; p < deg * 8; p += 64)    // p&7 == h8
            atab[w][p] = __expf(atab[w][p] - m) * rden;
        int e = 0;
        for (; e + 8 <= deg; e += 8) {
            ushort4 u[8]; float a[8];
            #pragma unroll
            for (int jj = 0; jj < 8; ++jj) {
                int s = stab[w][e + jj];
                u[jj] = *(const ushort4*)(h1 + (size_t)s * F1 + lane * 4);
                a[jj] = atab[w][(e + jj) * 8 + hh];
            }
            #pragma unroll
            for (int jj = 0; jj < 8; ++jj) {
                acc.x += a[jj] * bf2f(u[jj].x);
                acc.y += a[jj] * bf2f(u[jj].y);
                acc.z += a[jj] * bf2f(u[jj].z);
                acc.w += a[jj] * bf2f(u[jj].w);
            }
        }
        for (; e < deg; ++e) {
            int s = stab[w][e];
            float alpha = atab[w][e * 8 + hh];
            ushort4 u = *(const ushort4*)(h1 + (size_t)s * F1 + lane * 4);
            acc.x += alpha * bf2f(u.x); acc.y += alpha * bf2f(u.y);
            acc.z += alpha * bf2f(u.z); acc.w += alpha * bf2f(u.w);
        }
    } else {
        float m = -1e30f, den = 0.f;
        for (int i = beg + e8; i < end; i += 8) {
            int s = srcs[i];
            float v = lrelu(a1s[s * 8 + h8] + ad);
            float nm = fmaxf(m, v);
            den = den * __expf(m - nm) + __expf(v - nm);
            m = nm;
        }
        #pragma unroll
        for (int mask = 8; mask < 64; mask <<= 1) {
            float om = __shfl_xor(m, mask);
            float od = __shfl_xor(den, mask);
            float nm = fmaxf(m, om);
            den = den * __expf(m - nm) + od * __expf(om - nm);
            m = nm;
        }
        float rden = 1.f / (den + 1e-16f);
        for (int tb = beg; tb < end; tb += 64) {
            int cnt = min(64, end - tb);
            if (lane < cnt) stab[w][lane] = srcs[tb + lane];
            int np = cnt * 8;
            for (int p = lane; p < np; p += 64) {
                int s = stab[w][p >> 3];
                float v = lrelu(a1s[s * 8 + h8] + ad);
                atab[w][p] = __expf(v - m) * rden;
            }
            for (int e = 0; e < cnt; ++e) {
                int s = stab[w][e];
                float alpha = atab[w][e * 8 + hh];
                ushort4 u = *(const ushort4*)(h1 + (size_t)s * F1 + lane * 4);
                acc.x += alpha * bf2f(u.x); acc.y += alpha * bf2f(u.y);
                acc.z += alpha * bf2f(u.z); acc.w += alpha * bf2f(u.w);
            }
        }
    }
    float4 bb = *(const float4*)(b1 + lane * 4);
    ushort4 o;
    o.x = f2bf(acc.x + bb.x); o.y = f2bf(acc.y + bb.y);
    o.z = f2bf(acc.z + bb.z); o.w = f2bf(acc.w + bb.w);
    *(ushort4*)(out1 + (size_t)d * F1 + lane * 4) = o;
}

// agg2 over h3 = (h2)@Wo; writes FINAL fp32 out with bc = b2@Wo + bo.
__global__ __launch_bounds__(256) void k_agg2(
    const int* __restrict__ offsets, const int* __restrict__ srcs,
    const ushort* __restrict__ h3, const float* __restrict__ a2s,
    const float* __restrict__ a2d, const float* __restrict__ bc,
    float* __restrict__ out) {
    __shared__ float atab[4][64];
    __shared__ int   stab[4][64];
    const int w = threadIdx.x >> 6;
    const int d = blockIdx.x * 4 + w;
    if (d >= NN) return;
    const int lane = threadIdx.x & 63;
    const int beg = offsets[d], end = offsets[d + 1];
    const int deg = end - beg;
    const float ad = a2d[d];
    float2 acc = make_float2(0.f, 0.f);

    if (deg <= 64) {
        float m = -1e30f, den = 0.f;
        if (lane < deg) {
            int s = srcs[beg + lane];
            stab[w][lane] = s;
            float v = lrelu(a2s[s] + ad);
            atab[w][lane] = v;
            m = v;
            den = 1.f;
        }
        #pragma unroll
        for (int mask = 1; mask < 64; mask <<= 1) {
            float om = __shfl_xor(m, mask);
            float od = __shfl_xor(den, mask);
            float nm = fmaxf(m, om);
            den = den * __expf(m - nm) + od * __expf(om - nm);
            m = nm;
        }
        float rden = 1.f / (den + 1e-16f);
        if (lane < deg)
            atab[w][lane] = __expf(atab[w][lane] - m) * rden;
        int e = 0;
        for (; e + 8 <= deg; e += 8) {
            ushort2 u[8]; float a[8];
            #pragma unroll
            for (int jj = 0; jj < 8; ++jj) {
                int s = stab[w][e + jj];
                u[jj] = *(const ushort2*)(h3 + (size_t)s * F2 + lane * 2);
                a[jj] = atab[w][e + jj];
            }
            #pragma unroll
            for (int jj = 0; jj < 8; ++jj) {
                acc.x += a[jj] * bf2f(u[jj].x);
                acc.y += a[jj] * bf2f(u[jj].y);
            }
        }
        for (; e < deg; ++e) {
            int s = stab[w][e];
            float alpha = atab[w][e];
            ushort2 u = *(const ushort2*)(h3 + (size_t)s * F2 + lane * 2);
            acc.x += alpha * bf2f(u.x); acc.y += alpha * bf2f(u.y);
        }
    } else {
        float m = -1e30f, den = 0.f;
        for (int i = beg + lane; i < end; i += 64) {
            int s = srcs[i];
            float v = lrelu(a2s[s] + ad);
            float nm = fmaxf(m, v);
            den = den * __expf(m - nm) + __expf(v - nm);
            m = nm;
        }
        #pragma unroll
        for (int mask = 1; mask < 64; mask <<= 1) {
            float om = __shfl_xor(m, mask);
            float od = __shfl_xor(den, mask);
            float nm = fmaxf(m, om);
            den = den * __expf(m - nm) + od * __expf(om - nm);
            m = nm;
        }
        float rden = 1.f / (den + 1e-16f);
        for (int tb = beg; tb < end; tb += 64) {
            int cnt = min(64, end - tb);
            if (lane < cnt) {
                int s = srcs[tb + lane];
                stab[w][lane] = s;
                atab[w][lane] = __expf(lrelu(a2s[s] + ad) - m) * rden;
            }
            for (int e = 0; e < cnt; ++e) {
                int s = stab[w][e];
                float alpha = atab[w][e];
                ushort2 u = *(const ushort2*)(h3 + (size_t)s * F2 + lane * 2);
                acc.x += alpha * bf2f(u.x); acc.y += alpha * bf2f(u.y);
            }
        }
    }
    float2 bb = *(const float2*)(bc + lane * 2);
    *(float2*)(out + (size_t)d * F2 + lane * 2) = make_float2(acc.x + bb.x, acc.y + bb.y);
}

extern "C" void kernel_launch(void* const* d_in, const int* in_sizes, int n_in,
                              void* d_out, int out_size, void* d_ws, size_t ws_size,
                              hipStream_t stream) {
    const int*   x      = (const int*)d_in[0];
    const int*   edge   = (const int*)d_in[1];   // [2][E]
    const float* emb    = (const float*)d_in[2];
    const float* W1     = (const float*)d_in[3];
    const float* a_src1 = (const float*)d_in[4];
    const float* a_dst1 = (const float*)d_in[5];
    const float* b1     = (const float*)d_in[6];
    const float* W2     = (const float*)d_in[7];
    const float* a_src2 = (const float*)d_in[8];
    const float* a_dst2 = (const float*)d_in[9];
    const float* b2     = (const float*)d_in[10];
    const float* Wo     = (const float*)d_in[11];
    const float* bo     = (const float*)d_in[12];
    float* out = (float*)d_out;

    char* w = (char*)d_ws;
    auto alloc = [&](size_t bytes) {
        char* p = w;
        w += (bytes + 255) & ~(size_t)255;
        return p;
    };
    int*    offsets = (int*)alloc((NN + 1) * sizeof(int));
    int*    cursor  = (int*)alloc(NN * sizeof(int));
    int*    sums    = (int*)alloc(256 * sizeof(int));
    int*    srcs    = (int*)alloc((size_t)(EE + NN) * sizeof(int));
    ushort* W1t     = (ushort*)alloc((size_t)DD * F1 * sizeof(ushort));
    ushort* W2t     = (ushort*)alloc((size_t)F1 * F2 * sizeof(ushort));
    ushort* Wot     = (ushort*)alloc((size_t)F2 * F2 * sizeof(ushort));
    ushort* h1      = (ushort*)alloc((size_t)NN * F1 * sizeof(ushort));
    ushort* out1    = (ushort*)alloc((size_t)NN * F1 * sizeof(ushort));
    ushort* h3      = (ushort*)alloc((size_t)NN * F2 * sizeof(ushort));
    float*  a1s     = (float*)alloc((size_t)NN * 8 * sizeof(float));
    float*  a1d     = (float*)alloc((size_t)NN * 8 * sizeof(float));
    float*  bc      = (float*)alloc(F2 * sizeof(float));
    float*  a2s     = a1s;
    float*  a2d     = a1d;

    const int* esrc = edge;
    const int* edst = edge + EE;

    const int NB = (NN + 255) / 256;        // 196

    // CSR build + weight converts
    hipMemsetAsync(cursor, 0, NN * sizeof(int), stream);
    k_prep<<<HB + W1B + W2B + WOB + 1, 256, 0, stream>>>(
        edst, cursor, W1, W1t, W2, W2t, Wo, Wot, b2, bo, bc);
    k_scan1<<<NB, 256, 0, stream>>>(cursor, offsets, sums);
    k_scan3<<<NB, 256, 0, stream>>>(offsets, sums, cursor, NB);
    k_scatter<<<(EE + NN + 255) / 256, 256, 0, stream>>>(esrc, edst, offsets, cursor, srcs);

    const int MT = (NN + 127) / 128;        // 391

    // conv1 (GEMM + fused emb gather + al1)
    k_gemm1<<<dim3(MT, F1 / 128), 256, 0, stream>>>(
        x, emb, W1t, h1, a_src1, a_dst1, a1s, a1d);
    k_agg1<<<(NN + 3) / 4, 256, 0, stream>>>(offsets, srcs, h1, a1s, a1d, b1, out1);

    // conv2 GEMM + al2 + output linear fused: h3 = (out1@W2)@Wo
    k_gemm23<<<dim3(MT, 1), 256, 0, stream>>>(
        out1, W2t, Wot, h3, a_src2, a_dst2, a2s, a2d);

    // final aggregation writes fp32 out directly
    k_agg2<<<(NN + 3) / 4, 256, 0, stream>>>(offsets, srcs, h3, a2s, a2d, bc, out);
}